// Round 1
// baseline (1165.457 us; speedup 1.0000x reference)
//
#include <hip/hip_runtime.h>
#include <math.h>

#define NH 8
#define HD 64
#define NSEQ 1024
#define DMODEL 512
#define F3 1536
#define NTOK 16384
#define BH 128   // (B*T)*NH = 16*8

__device__ __forceinline__ float freq_of(int j) {
    // pi * linspace(1, 128, 16)[j]
    return 3.14159265358979323846f * (1.0f + (float)j * (127.0f / 15.0f));
}

// ---------------- Kernel 1: QKV GEMM + axial RoPE ----------------
// C[m][f] = sum_c x[m][c] * w_qkv[f][c];  m in [0,16384), f in [0,1536)
// Tile 64x64, BK=16, 256 threads, 4x4 micro-tile.
// Epilogue: split into q/k/v head layout (bt, head, n, dd), rope on q,k.
__global__ __launch_bounds__(256) void qkv_rope_kernel(
        const float* __restrict__ x, const float* __restrict__ wq,
        float* __restrict__ q_ws, float* __restrict__ k_ws, float* __restrict__ v_ws) {
    __shared__ float As[16][68];  // [c][m], padded, rows 16B-aligned
    __shared__ float Bs[16][68];  // [c][f]
    const int m0 = blockIdx.x * 64;
    const int f0 = blockIdx.y * 64;
    const int t = threadIdx.x;
    const int tx = t & 15, ty = t >> 4;
    float acc[4][4] = {{0.f}};
    for (int c0 = 0; c0 < DMODEL; c0 += 16) {
        for (int l = t; l < 1024; l += 256) {
            const int ml = l >> 4, cl = l & 15;
            As[cl][ml] = x[(size_t)(m0 + ml) * DMODEL + c0 + cl];
        }
        for (int l = t; l < 1024; l += 256) {
            const int fl = l >> 4, cl = l & 15;
            Bs[cl][fl] = wq[(size_t)(f0 + fl) * DMODEL + c0 + cl];
        }
        __syncthreads();
        #pragma unroll
        for (int kk = 0; kk < 16; kk++) {
            const float4 a = *(const float4*)&As[kk][ty * 4];
            const float4 b = *(const float4*)&Bs[kk][tx * 4];
            acc[0][0] = fmaf(a.x, b.x, acc[0][0]);
            acc[0][1] = fmaf(a.x, b.y, acc[0][1]);
            acc[0][2] = fmaf(a.x, b.z, acc[0][2]);
            acc[0][3] = fmaf(a.x, b.w, acc[0][3]);
            acc[1][0] = fmaf(a.y, b.x, acc[1][0]);
            acc[1][1] = fmaf(a.y, b.y, acc[1][1]);
            acc[1][2] = fmaf(a.y, b.z, acc[1][2]);
            acc[1][3] = fmaf(a.y, b.w, acc[1][3]);
            acc[2][0] = fmaf(a.z, b.x, acc[2][0]);
            acc[2][1] = fmaf(a.z, b.y, acc[2][1]);
            acc[2][2] = fmaf(a.z, b.z, acc[2][2]);
            acc[2][3] = fmaf(a.z, b.w, acc[2][3]);
            acc[3][0] = fmaf(a.w, b.x, acc[3][0]);
            acc[3][1] = fmaf(a.w, b.y, acc[3][1]);
            acc[3][2] = fmaf(a.w, b.z, acc[3][2]);
            acc[3][3] = fmaf(a.w, b.w, acc[3][3]);
        }
        __syncthreads();
    }
    // epilogue: this tile is exactly one (sel, head) since f0 % 64 == 0
    const int sel = f0 >> 9;            // 0=q, 1=k, 2=v
    const int head = (f0 >> 6) & 7;
    float* base = (sel == 0) ? q_ws : ((sel == 1) ? k_ws : v_ws);
    const int dd0 = tx * 4;             // dims [dd0, dd0+3], pairs (dd0,dd0+1),(dd0+2,dd0+3)
    #pragma unroll
    for (int i = 0; i < 4; i++) {
        const int m = m0 + ty * 4 + i;
        const int bt = m >> 10, n = m & 1023;
        float4 r = make_float4(acc[i][0], acc[i][1], acc[i][2], acc[i][3]);
        if (sel != 2) {
            const int y = n >> 5, xw = n & 31;
            const float pos = (dd0 < 32) ? (-1.0f + (float)y * (2.0f / 31.0f))
                                         : (-1.0f + (float)xw * (2.0f / 31.0f));
            const int j0 = (dd0 < 32) ? (dd0 >> 1) : ((dd0 - 32) >> 1);
            float s0, c0a, s1, c1a;
            sincosf(pos * freq_of(j0), &s0, &c0a);
            sincosf(pos * freq_of(j0 + 1), &s1, &c1a);
            r = make_float4(acc[i][0] * c0a - acc[i][1] * s0,
                            acc[i][1] * c0a + acc[i][0] * s0,
                            acc[i][2] * c1a - acc[i][3] * s1,
                            acc[i][3] * c1a + acc[i][2] * s1);
        }
        *(float4*)(base + ((size_t)(bt * NH + head) * NSEQ + n) * HD + dd0) = r;
    }
}

// ---------------- Kernel 2: flash attention ----------------
// One block: 64 q-rows of one (bt,head); loops over 16 kv tiles of 64.
// LDS: Qs row-major (broadcast reads), KP = K^T (float4 B reads) reused for P,
// Vs row-major. 256 threads, 4x4 micro-tile.
__global__ __launch_bounds__(256) void attn_kernel(
        const float* __restrict__ q_ws, const float* __restrict__ k_ws,
        const float* __restrict__ v_ws, float* __restrict__ o_ws) {
    __shared__ float Qs[64][65];   // [qrow][dd]
    __shared__ float KP[64][68];   // phase1: [dd][kcol]; phase2: P [qrow][kcol]
    __shared__ float Vs[64][68];   // [krow][dd]
    const int qt = blockIdx.x;     // 0..15
    const int bh = blockIdx.y;     // 0..127
    const int t = threadIdx.x;
    const int tx = t & 15, ty = t >> 4;
    const float scale = 0.125f;    // 64^-0.5

    const float* qbase = q_ws + ((size_t)bh * NSEQ + qt * 64) * HD;
    const float* kbase = k_ws + (size_t)bh * NSEQ * HD;
    const float* vbase = v_ws + (size_t)bh * NSEQ * HD;

    for (int l = t; l < 1024; l += 256) {
        const int r = l >> 4, dd4 = (l & 15) * 4;
        const float4 qv = *(const float4*)(qbase + (size_t)r * HD + dd4);
        Qs[r][dd4 + 0] = qv.x; Qs[r][dd4 + 1] = qv.y;
        Qs[r][dd4 + 2] = qv.z; Qs[r][dd4 + 3] = qv.w;
    }

    float o[4][4] = {{0.f}};
    float m_i[4] = {-1e30f, -1e30f, -1e30f, -1e30f};
    float l_i[4] = {0.f, 0.f, 0.f, 0.f};

    for (int kt = 0; kt < 16; kt++) {
        __syncthreads();  // previous tile's KP/Vs reads done (also covers Q load, iter 0)
        for (int l = t; l < 1024; l += 256) {
            const int r = l >> 4, dd4 = (l & 15) * 4;
            const float4 kv = *(const float4*)(kbase + (size_t)(kt * 64 + r) * HD + dd4);
            KP[dd4 + 0][r] = kv.x; KP[dd4 + 1][r] = kv.y;
            KP[dd4 + 2][r] = kv.z; KP[dd4 + 3][r] = kv.w;
            *(float4*)&Vs[r][dd4] =
                *(const float4*)(vbase + (size_t)(kt * 64 + r) * HD + dd4);
        }
        __syncthreads();
        float s[4][4] = {{0.f}};
        #pragma unroll 8
        for (int kk = 0; kk < 64; kk++) {
            const float4 b = *(const float4*)&KP[kk][tx * 4];
            const float a0 = Qs[ty * 4 + 0][kk];
            const float a1 = Qs[ty * 4 + 1][kk];
            const float a2 = Qs[ty * 4 + 2][kk];
            const float a3 = Qs[ty * 4 + 3][kk];
            s[0][0] = fmaf(a0, b.x, s[0][0]); s[0][1] = fmaf(a0, b.y, s[0][1]);
            s[0][2] = fmaf(a0, b.z, s[0][2]); s[0][3] = fmaf(a0, b.w, s[0][3]);
            s[1][0] = fmaf(a1, b.x, s[1][0]); s[1][1] = fmaf(a1, b.y, s[1][1]);
            s[1][2] = fmaf(a1, b.z, s[1][2]); s[1][3] = fmaf(a1, b.w, s[1][3]);
            s[2][0] = fmaf(a2, b.x, s[2][0]); s[2][1] = fmaf(a2, b.y, s[2][1]);
            s[2][2] = fmaf(a2, b.z, s[2][2]); s[2][3] = fmaf(a2, b.w, s[2][3]);
            s[3][0] = fmaf(a3, b.x, s[3][0]); s[3][1] = fmaf(a3, b.y, s[3][1]);
            s[3][2] = fmaf(a3, b.z, s[3][2]); s[3][3] = fmaf(a3, b.w, s[3][3]);
        }
        __syncthreads();  // all S reads of K done before P overwrites KP
        #pragma unroll
        for (int i = 0; i < 4; i++) {
            float v0 = s[i][0] * scale, v1 = s[i][1] * scale;
            float v2 = s[i][2] * scale, v3 = s[i][3] * scale;
            float mt = fmaxf(fmaxf(v0, v1), fmaxf(v2, v3));
            #pragma unroll
            for (int off = 1; off < 16; off <<= 1) mt = fmaxf(mt, __shfl_xor(mt, off));
            const float mnew = fmaxf(m_i[i], mt);
            const float alpha = __expf(m_i[i] - mnew);
            v0 = __expf(v0 - mnew); v1 = __expf(v1 - mnew);
            v2 = __expf(v2 - mnew); v3 = __expf(v3 - mnew);
            float ls = v0 + v1 + v2 + v3;
            #pragma unroll
            for (int off = 1; off < 16; off <<= 1) ls += __shfl_xor(ls, off);
            l_i[i] = l_i[i] * alpha + ls;
            m_i[i] = mnew;
            o[i][0] *= alpha; o[i][1] *= alpha; o[i][2] *= alpha; o[i][3] *= alpha;
            *(float4*)&KP[ty * 4 + i][tx * 4] = make_float4(v0, v1, v2, v3);
        }
        __syncthreads();
        #pragma unroll 8
        for (int kk = 0; kk < 64; kk++) {
            const float4 b = *(const float4*)&Vs[kk][tx * 4];
            const float a0 = KP[ty * 4 + 0][kk];
            const float a1 = KP[ty * 4 + 1][kk];
            const float a2 = KP[ty * 4 + 2][kk];
            const float a3 = KP[ty * 4 + 3][kk];
            o[0][0] = fmaf(a0, b.x, o[0][0]); o[0][1] = fmaf(a0, b.y, o[0][1]);
            o[0][2] = fmaf(a0, b.z, o[0][2]); o[0][3] = fmaf(a0, b.w, o[0][3]);
            o[1][0] = fmaf(a1, b.x, o[1][0]); o[1][1] = fmaf(a1, b.y, o[1][1]);
            o[1][2] = fmaf(a1, b.z, o[1][2]); o[1][3] = fmaf(a1, b.w, o[1][3]);
            o[2][0] = fmaf(a2, b.x, o[2][0]); o[2][1] = fmaf(a2, b.y, o[2][1]);
            o[2][2] = fmaf(a2, b.z, o[2][2]); o[2][3] = fmaf(a2, b.w, o[2][3]);
            o[3][0] = fmaf(a3, b.x, o[3][0]); o[3][1] = fmaf(a3, b.y, o[3][1]);
            o[3][2] = fmaf(a3, b.z, o[3][2]); o[3][3] = fmaf(a3, b.w, o[3][3]);
        }
    }
    float* obase = o_ws + ((size_t)bh * NSEQ + qt * 64) * HD;
    #pragma unroll
    for (int i = 0; i < 4; i++) {
        const float inv = 1.0f / l_i[i];
        *(float4*)(obase + (size_t)(ty * 4 + i) * HD + tx * 4) =
            make_float4(o[i][0] * inv, o[i][1] * inv, o[i][2] * inv, o[i][3] * inv);
    }
}

// ---------------- Kernel 3: output projection ----------------
// out[m][dout] = sum_f o[m][f] * w_out[dout][f] + b_out[dout]
__global__ __launch_bounds__(256) void proj_kernel(
        const float* __restrict__ o_ws, const float* __restrict__ w_out,
        const float* __restrict__ b_out, float* __restrict__ out) {
    __shared__ float As[16][68];
    __shared__ float Bs[16][68];
    const int m0 = blockIdx.x * 64;
    const int f0 = blockIdx.y * 64;
    const int t = threadIdx.x;
    const int tx = t & 15, ty = t >> 4;
    float acc[4][4] = {{0.f}};
    for (int c0 = 0; c0 < DMODEL; c0 += 16) {
        const int head = c0 >> 6;
        const int ddb = c0 & 63;
        for (int l = t; l < 1024; l += 256) {
            const int ml = l >> 4, cl = l & 15;
            const int m = m0 + ml;
            const int bt = m >> 10, n = m & 1023;
            As[cl][ml] = o_ws[((size_t)(bt * NH + head) * NSEQ + n) * HD + ddb + cl];
        }
        for (int l = t; l < 1024; l += 256) {
            const int fl = l >> 4, cl = l & 15;
            Bs[cl][fl] = w_out[(size_t)(f0 + fl) * DMODEL + c0 + cl];
        }
        __syncthreads();
        #pragma unroll
        for (int kk = 0; kk < 16; kk++) {
            const float4 a = *(const float4*)&As[kk][ty * 4];
            const float4 b = *(const float4*)&Bs[kk][tx * 4];
            acc[0][0] = fmaf(a.x, b.x, acc[0][0]);
            acc[0][1] = fmaf(a.x, b.y, acc[0][1]);
            acc[0][2] = fmaf(a.x, b.z, acc[0][2]);
            acc[0][3] = fmaf(a.x, b.w, acc[0][3]);
            acc[1][0] = fmaf(a.y, b.x, acc[1][0]);
            acc[1][1] = fmaf(a.y, b.y, acc[1][1]);
            acc[1][2] = fmaf(a.y, b.z, acc[1][2]);
            acc[1][3] = fmaf(a.y, b.w, acc[1][3]);
            acc[2][0] = fmaf(a.z, b.x, acc[2][0]);
            acc[2][1] = fmaf(a.z, b.y, acc[2][1]);
            acc[2][2] = fmaf(a.z, b.z, acc[2][2]);
            acc[2][3] = fmaf(a.z, b.w, acc[2][3]);
            acc[3][0] = fmaf(a.w, b.x, acc[3][0]);
            acc[3][1] = fmaf(a.w, b.y, acc[3][1]);
            acc[3][2] = fmaf(a.w, b.z, acc[3][2]);
            acc[3][3] = fmaf(a.w, b.w, acc[3][3]);
        }
        __syncthreads();
    }
    const float4 bias = *(const float4*)(b_out + f0 + tx * 4);
    #pragma unroll
    for (int i = 0; i < 4; i++) {
        const int m = m0 + ty * 4 + i;
        *(float4*)(out + (size_t)m * DMODEL + f0 + tx * 4) =
            make_float4(acc[i][0] + bias.x, acc[i][1] + bias.y,
                        acc[i][2] + bias.z, acc[i][3] + bias.w);
    }
}

extern "C" void kernel_launch(void* const* d_in, const int* in_sizes, int n_in,
                              void* d_out, int out_size, void* d_ws, size_t ws_size,
                              hipStream_t stream) {
    const float* x  = (const float*)d_in[0];
    const float* wq = (const float*)d_in[1];
    const float* wo = (const float*)d_in[2];
    const float* bo = (const float*)d_in[3];
    float* out = (float*)d_out;
    float* ws = (float*)d_ws;
    const size_t per = (size_t)BH * NSEQ * HD;  // 8,388,608 floats (32 MiB)
    float* q_ws = ws;
    float* k_ws = q_ws + per;
    float* v_ws = k_ws + per;
    float* o_ws = v_ws + per;   // total 128 MiB of workspace

    qkv_rope_kernel<<<dim3(NTOK / 64, F3 / 64), 256, 0, stream>>>(x, wq, q_ws, k_ws, v_ws);
    attn_kernel<<<dim3(16, BH), 256, 0, stream>>>(q_ws, k_ws, v_ws, o_ws);
    proj_kernel<<<dim3(NTOK / 64, DMODEL / 64), 256, 0, stream>>>(o_ws, wo, bo, out);
}

// Round 2
// 865.950 us; speedup vs baseline: 1.3459x; 1.3459x over previous
//
#include <hip/hip_runtime.h>
#include <math.h>

#define NH 8
#define HD 64
#define NSEQ 1024
#define DMODEL 512
#define F3 1536
#define NTOK 16384
#define BH 128   // (B*T)*NH = 16*8
#define PITCH 72 // bf16 LDS row pitch (144 B, 16B-aligned, breaks pow2 strides)

typedef __attribute__((ext_vector_type(8))) short bf16x8;
typedef __attribute__((ext_vector_type(4))) float f32x4;
#define MFMA16(a, b, c) __builtin_amdgcn_mfma_f32_16x16x32_bf16(a, b, c, 0, 0, 0)

__device__ __forceinline__ float freq_of(int j) {
    // pi * linspace(1, 128, 16)[j]
    return 3.14159265358979323846f * (1.0f + (float)j * (127.0f / 15.0f));
}

__device__ __forceinline__ unsigned short bf16_hi(float x) {
    unsigned u = __builtin_bit_cast(unsigned, x);
    return (unsigned short)(u >> 16);   // truncation split: residual captured by lo
}
__device__ __forceinline__ float bf16_tofloat(unsigned short h) {
    unsigned u = ((unsigned)h) << 16;
    return __builtin_bit_cast(float, u);
}

// ---------------- Kernel 1: QKV GEMM + axial RoPE + bf16 hi/lo split ----------------
// C[m][f] = sum_c x[m][c] * w_qkv[f][c];  m in [0,16384), f in [0,1536)
// Epilogue: q,k -> rope -> split bf16 hi/lo, layout [bh][n][dd].
//           v   -> split bf16 hi/lo, TRANSPOSED layout [bh][dd][n] (via LDS).
__global__ __launch_bounds__(256) void qkv_rope_kernel(
        const float* __restrict__ x, const float* __restrict__ wq,
        unsigned short* __restrict__ q_hi, unsigned short* __restrict__ q_lo,
        unsigned short* __restrict__ k_hi, unsigned short* __restrict__ k_lo,
        unsigned short* __restrict__ v_th, unsigned short* __restrict__ v_tl) {
    __shared__ float smem[2304];                       // 9216 B
    float (*As)[68] = (float(*)[68])smem;              // [16][68]
    float (*Bs)[68] = (float(*)[68])(smem + 1088);     // [16][68]
    unsigned short* Ts = (unsigned short*)smem;        // 64 x PITCH bf16 transpose buffer

    const int m0 = blockIdx.x * 64;
    const int f0 = blockIdx.y * 64;
    const int t = threadIdx.x;
    const int tx = t & 15, ty = t >> 4;
    float acc[4][4] = {{0.f}};
    for (int c0 = 0; c0 < DMODEL; c0 += 16) {
        for (int l = t; l < 1024; l += 256) {
            const int ml = l >> 4, cl = l & 15;
            As[cl][ml] = x[(size_t)(m0 + ml) * DMODEL + c0 + cl];
        }
        for (int l = t; l < 1024; l += 256) {
            const int fl = l >> 4, cl = l & 15;
            Bs[cl][fl] = wq[(size_t)(f0 + fl) * DMODEL + c0 + cl];
        }
        __syncthreads();
        #pragma unroll
        for (int kk = 0; kk < 16; kk++) {
            const float4 a = *(const float4*)&As[kk][ty * 4];
            const float4 b = *(const float4*)&Bs[kk][tx * 4];
            acc[0][0] = fmaf(a.x, b.x, acc[0][0]);
            acc[0][1] = fmaf(a.x, b.y, acc[0][1]);
            acc[0][2] = fmaf(a.x, b.z, acc[0][2]);
            acc[0][3] = fmaf(a.x, b.w, acc[0][3]);
            acc[1][0] = fmaf(a.y, b.x, acc[1][0]);
            acc[1][1] = fmaf(a.y, b.y, acc[1][1]);
            acc[1][2] = fmaf(a.y, b.z, acc[1][2]);
            acc[1][3] = fmaf(a.y, b.w, acc[1][3]);
            acc[2][0] = fmaf(a.z, b.x, acc[2][0]);
            acc[2][1] = fmaf(a.z, b.y, acc[2][1]);
            acc[2][2] = fmaf(a.z, b.z, acc[2][2]);
            acc[2][3] = fmaf(a.z, b.w, acc[2][3]);
            acc[3][0] = fmaf(a.w, b.x, acc[3][0]);
            acc[3][1] = fmaf(a.w, b.y, acc[3][1]);
            acc[3][2] = fmaf(a.w, b.z, acc[3][2]);
            acc[3][3] = fmaf(a.w, b.w, acc[3][3]);
        }
        __syncthreads();
    }
    const int sel = f0 >> 9;            // 0=q, 1=k, 2=v
    const int head = (f0 >> 6) & 7;
    if (sel != 2) {
        unsigned short* hbase = (sel == 0) ? q_hi : k_hi;
        unsigned short* lbase = (sel == 0) ? q_lo : k_lo;
        const int dd0 = tx * 4;
        #pragma unroll
        for (int i = 0; i < 4; i++) {
            const int m = m0 + ty * 4 + i;
            const int bt = m >> 10, n = m & 1023;
            const int y = n >> 5, xw = n & 31;
            const float pos = (dd0 < 32) ? (-1.0f + (float)y * (2.0f / 31.0f))
                                         : (-1.0f + (float)xw * (2.0f / 31.0f));
            const int j0 = (dd0 < 32) ? (dd0 >> 1) : ((dd0 - 32) >> 1);
            float s0, c0a, s1, c1a;
            sincosf(pos * freq_of(j0), &s0, &c0a);
            sincosf(pos * freq_of(j0 + 1), &s1, &c1a);
            float r[4];
            r[0] = acc[i][0] * c0a - acc[i][1] * s0;
            r[1] = acc[i][1] * c0a + acc[i][0] * s0;
            r[2] = acc[i][2] * c1a - acc[i][3] * s1;
            r[3] = acc[i][3] * c1a + acc[i][2] * s1;
            unsigned short hv[4], lv[4];
            #pragma unroll
            for (int c = 0; c < 4; c++) {
                hv[c] = bf16_hi(r[c]);
                lv[c] = bf16_hi(r[c] - bf16_tofloat(hv[c]));
            }
            const size_t dst = ((size_t)(bt * NH + head) * NSEQ + n) * HD + dd0;
            *(ushort4*)(hbase + dst) = make_ushort4(hv[0], hv[1], hv[2], hv[3]);
            *(ushort4*)(lbase + dst) = make_ushort4(lv[0], lv[1], lv[2], lv[3]);
        }
    } else {
        // V: transpose 64x64 tile through LDS, write [bh][dd][n] hi then lo
        const int bt = m0 >> 10, n0 = m0 & 1023;
        const size_t gbase = ((size_t)(bt * NH + head) * HD) * NSEQ + n0;
        // pass 1: hi
        #pragma unroll
        for (int i = 0; i < 4; i++)
            #pragma unroll
            for (int c = 0; c < 4; c++)
                Ts[(tx * 4 + c) * PITCH + ty * 4 + i] = bf16_hi(acc[i][c]);
        __syncthreads();
        #pragma unroll
        for (int p = 0; p < 2; p++) {
            const int cc = t + p * 256;
            const int dd = cc >> 3, off8 = (cc & 7) * 8;
            *(uint4*)(v_th + gbase + (size_t)dd * NSEQ + off8) =
                *(const uint4*)&Ts[dd * PITCH + off8];
        }
        __syncthreads();
        // pass 2: lo
        #pragma unroll
        for (int i = 0; i < 4; i++)
            #pragma unroll
            for (int c = 0; c < 4; c++) {
                const float h = bf16_tofloat(bf16_hi(acc[i][c]));
                Ts[(tx * 4 + c) * PITCH + ty * 4 + i] = bf16_hi(acc[i][c] - h);
            }
        __syncthreads();
        #pragma unroll
        for (int p = 0; p < 2; p++) {
            const int cc = t + p * 256;
            const int dd = cc >> 3, off8 = (cc & 7) * 8;
            *(uint4*)(v_tl + gbase + (size_t)dd * NSEQ + off8) =
                *(const uint4*)&Ts[dd * PITCH + off8];
        }
    }
}

// ---------------- Kernel 2: flash attention, split-bf16 MFMA ----------------
// Block = 256 threads = 4 waves; wave w owns q rows [16w,16w+16) of a 64-row tile.
// mfma_f32_16x16x32_bf16 layouts (verified m89/m91/m120):
//   A[m=lane&15][k=quad*8+j], B[k=quad*8+j][n=lane&15], D[m=quad*4+reg][n=lane&15]
__global__ __launch_bounds__(256) void attn_kernel(
        const unsigned short* __restrict__ q_hi, const unsigned short* __restrict__ q_lo,
        const unsigned short* __restrict__ k_hi, const unsigned short* __restrict__ k_lo,
        const unsigned short* __restrict__ v_th, const unsigned short* __restrict__ v_tl,
        float* __restrict__ o_ws) {
    __shared__ unsigned short KPh[64 * PITCH];  // K tile (rows) -> then P_hi tile
    __shared__ unsigned short KPl[64 * PITCH];  // K_lo -> P_lo
    __shared__ unsigned short Vsh[64 * PITCH];  // V^T tile hi: [dd][j]
    __shared__ unsigned short Vsl[64 * PITCH];  // V^T tile lo

    const int qt = blockIdx.x;     // 0..15
    const int bh = blockIdx.y;     // 0..127
    const int t = threadIdx.x;
    const int w = t >> 6;          // wave 0..3
    const int lane = t & 63;
    const int l15 = lane & 15;
    const int quad = lane >> 4;
    const float scale = 0.125f;

    const size_t bh_nd = (size_t)bh * NSEQ * HD;        // [bh][n][dd] base
    const size_t bh_dn = (size_t)bh * HD * NSEQ;        // [bh][dd][n] base

    // ---- stage Q tile into KP buffers, read A-fragments once ----
    #pragma unroll
    for (int p = 0; p < 2; p++) {
        const int cc = t + p * 256;
        const int r = cc >> 3, off8 = (cc & 7) * 8;
        const size_t g = bh_nd + (size_t)(qt * 64 + r) * HD + off8;
        *(uint4*)&KPh[r * PITCH + off8] = *(const uint4*)(q_hi + g);
        *(uint4*)&KPl[r * PITCH + off8] = *(const uint4*)(q_lo + g);
    }
    __syncthreads();
    bf16x8 qfh[2], qfl[2];
    {
        const int r = w * 16 + l15;
        #pragma unroll
        for (int ks = 0; ks < 2; ks++) {
            qfh[ks] = *(const bf16x8*)&KPh[r * PITCH + ks * 32 + quad * 8];
            qfl[ks] = *(const bf16x8*)&KPl[r * PITCH + ks * 32 + quad * 8];
        }
    }

    f32x4 o_acc[4];
    #pragma unroll
    for (int dt = 0; dt < 4; dt++) o_acc[dt] = (f32x4){0.f, 0.f, 0.f, 0.f};
    float m_i[4] = {-1e30f, -1e30f, -1e30f, -1e30f};
    float l_i[4] = {0.f, 0.f, 0.f, 0.f};

    for (int kt = 0; kt < 16; kt++) {
        __syncthreads();   // Q-frag reads (kt=0) / prev PV reads complete
        #pragma unroll
        for (int p = 0; p < 2; p++) {
            const int cc = t + p * 256;
            const int r = cc >> 3, off8 = (cc & 7) * 8;
            const size_t gk = bh_nd + (size_t)(kt * 64 + r) * HD + off8;
            *(uint4*)&KPh[r * PITCH + off8] = *(const uint4*)(k_hi + gk);
            *(uint4*)&KPl[r * PITCH + off8] = *(const uint4*)(k_lo + gk);
            const size_t gv = bh_dn + (size_t)r * NSEQ + kt * 64 + off8;
            *(uint4*)&Vsh[r * PITCH + off8] = *(const uint4*)(v_th + gv);
            *(uint4*)&Vsl[r * PITCH + off8] = *(const uint4*)(v_tl + gv);
        }
        __syncthreads();

        // ---- S = Q K^T (split: hh + hl + lh) ----
        f32x4 s[4];
        #pragma unroll
        for (int nt = 0; nt < 4; nt++) {
            s[nt] = (f32x4){0.f, 0.f, 0.f, 0.f};
            #pragma unroll
            for (int ks = 0; ks < 2; ks++) {
                const int boff = (nt * 16 + l15) * PITCH + ks * 32 + quad * 8;
                const bf16x8 kbh = *(const bf16x8*)&KPh[boff];
                const bf16x8 kbl = *(const bf16x8*)&KPl[boff];
                s[nt] = MFMA16(qfh[ks], kbh, s[nt]);
                s[nt] = MFMA16(qfh[ks], kbl, s[nt]);
                s[nt] = MFMA16(qfl[ks], kbh, s[nt]);
            }
        }
        __syncthreads();   // all K reads done before P overwrites KP

        // ---- online softmax (rows = 16w + quad*4 + r) ----
        #pragma unroll
        for (int r = 0; r < 4; r++) {
            float v0 = s[0][r] * scale, v1 = s[1][r] * scale;
            float v2 = s[2][r] * scale, v3 = s[3][r] * scale;
            float mt = fmaxf(fmaxf(v0, v1), fmaxf(v2, v3));
            #pragma unroll
            for (int off = 1; off < 16; off <<= 1) mt = fmaxf(mt, __shfl_xor(mt, off));
            const float mnew = fmaxf(m_i[r], mt);
            const float alpha = __expf(m_i[r] - mnew);
            const float e0 = __expf(v0 - mnew), e1 = __expf(v1 - mnew);
            const float e2 = __expf(v2 - mnew), e3 = __expf(v3 - mnew);
            float ls = e0 + e1 + e2 + e3;
            #pragma unroll
            for (int off = 1; off < 16; off <<= 1) ls += __shfl_xor(ls, off);
            l_i[r] = l_i[r] * alpha + ls;
            m_i[r] = mnew;
            #pragma unroll
            for (int dt = 0; dt < 4; dt++) {
                o_acc[dt][r] *= alpha;
            }
            const int prow = w * 16 + quad * 4 + r;
            const float ev[4] = {e0, e1, e2, e3};
            #pragma unroll
            for (int nt = 0; nt < 4; nt++) {
                const int col = nt * 16 + l15;
                const unsigned short hb = bf16_hi(ev[nt]);
                KPh[prow * PITCH + col] = hb;
                KPl[prow * PITCH + col] = bf16_hi(ev[nt] - bf16_tofloat(hb));
            }
        }
        __syncthreads();

        // ---- O += P V (split: hh + hl + lh) ----
        bf16x8 pfh[2], pfl[2];
        {
            const int pr = w * 16 + l15;
            #pragma unroll
            for (int ks = 0; ks < 2; ks++) {
                pfh[ks] = *(const bf16x8*)&KPh[pr * PITCH + ks * 32 + quad * 8];
                pfl[ks] = *(const bf16x8*)&KPl[pr * PITCH + ks * 32 + quad * 8];
            }
        }
        #pragma unroll
        for (int dt = 0; dt < 4; dt++) {
            #pragma unroll
            for (int ks = 0; ks < 2; ks++) {
                const int voff = (dt * 16 + l15) * PITCH + ks * 32 + quad * 8;
                const bf16x8 vbh = *(const bf16x8*)&Vsh[voff];
                const bf16x8 vbl = *(const bf16x8*)&Vsl[voff];
                o_acc[dt] = MFMA16(pfh[ks], vbh, o_acc[dt]);
                o_acc[dt] = MFMA16(pfh[ks], vbl, o_acc[dt]);
                o_acc[dt] = MFMA16(pfl[ks], vbh, o_acc[dt]);
            }
        }
    }

    // ---- epilogue: normalize, store fp32 [bh][n][dd] ----
    #pragma unroll
    for (int r = 0; r < 4; r++) {
        const float inv = 1.0f / l_i[r];
        const int row = qt * 64 + w * 16 + quad * 4 + r;
        #pragma unroll
        for (int dt = 0; dt < 4; dt++) {
            o_ws[((size_t)bh * NSEQ + row) * HD + dt * 16 + l15] = o_acc[dt][r] * inv;
        }
    }
}

// ---------------- Kernel 3: output projection ----------------
__global__ __launch_bounds__(256) void proj_kernel(
        const float* __restrict__ o_ws, const float* __restrict__ w_out,
        const float* __restrict__ b_out, float* __restrict__ out) {
    __shared__ float As[16][68];
    __shared__ float Bs[16][68];
    const int m0 = blockIdx.x * 64;
    const int f0 = blockIdx.y * 64;
    const int t = threadIdx.x;
    const int tx = t & 15, ty = t >> 4;
    float acc[4][4] = {{0.f}};
    for (int c0 = 0; c0 < DMODEL; c0 += 16) {
        const int head = c0 >> 6;
        const int ddb = c0 & 63;
        for (int l = t; l < 1024; l += 256) {
            const int ml = l >> 4, cl = l & 15;
            const int m = m0 + ml;
            const int bt = m >> 10, n = m & 1023;
            As[cl][ml] = o_ws[((size_t)(bt * NH + head) * NSEQ + n) * HD + ddb + cl];
        }
        for (int l = t; l < 1024; l += 256) {
            const int fl = l >> 4, cl = l & 15;
            Bs[cl][fl] = w_out[(size_t)(f0 + fl) * DMODEL + c0 + cl];
        }
        __syncthreads();
        #pragma unroll
        for (int kk = 0; kk < 16; kk++) {
            const float4 a = *(const float4*)&As[kk][ty * 4];
            const float4 b = *(const float4*)&Bs[kk][tx * 4];
            acc[0][0] = fmaf(a.x, b.x, acc[0][0]);
            acc[0][1] = fmaf(a.x, b.y, acc[0][1]);
            acc[0][2] = fmaf(a.x, b.z, acc[0][2]);
            acc[0][3] = fmaf(a.x, b.w, acc[0][3]);
            acc[1][0] = fmaf(a.y, b.x, acc[1][0]);
            acc[1][1] = fmaf(a.y, b.y, acc[1][1]);
            acc[1][2] = fmaf(a.y, b.z, acc[1][2]);
            acc[1][3] = fmaf(a.y, b.w, acc[1][3]);
            acc[2][0] = fmaf(a.z, b.x, acc[2][0]);
            acc[2][1] = fmaf(a.z, b.y, acc[2][1]);
            acc[2][2] = fmaf(a.z, b.z, acc[2][2]);
            acc[2][3] = fmaf(a.z, b.w, acc[2][3]);
            acc[3][0] = fmaf(a.w, b.x, acc[3][0]);
            acc[3][1] = fmaf(a.w, b.y, acc[3][1]);
            acc[3][2] = fmaf(a.w, b.z, acc[3][2]);
            acc[3][3] = fmaf(a.w, b.w, acc[3][3]);
        }
        __syncthreads();
    }
    const float4 bias = *(const float4*)(b_out + f0 + tx * 4);
    #pragma unroll
    for (int i = 0; i < 4; i++) {
        const int m = m0 + ty * 4 + i;
        *(float4*)(out + (size_t)m * DMODEL + f0 + tx * 4) =
            make_float4(acc[i][0] + bias.x, acc[i][1] + bias.y,
                        acc[i][2] + bias.z, acc[i][3] + bias.w);
    }
}

extern "C" void kernel_launch(void* const* d_in, const int* in_sizes, int n_in,
                              void* d_out, int out_size, void* d_ws, size_t ws_size,
                              hipStream_t stream) {
    const float* x  = (const float*)d_in[0];
    const float* wq = (const float*)d_in[1];
    const float* wo = (const float*)d_in[2];
    const float* bo = (const float*)d_in[3];
    float* out = (float*)d_out;

    const size_t per_bf = (size_t)BH * NSEQ * HD;          // 8,388,608 bf16 = 16 MiB
    unsigned short* q_hi = (unsigned short*)d_ws;
    unsigned short* q_lo = q_hi + per_bf;
    unsigned short* k_hi = q_lo + per_bf;
    unsigned short* k_lo = k_hi + per_bf;
    unsigned short* v_th = k_lo + per_bf;
    unsigned short* v_tl = v_th + per_bf;                  // 96 MiB bf16 total
    float* o_ws = (float*)(v_tl + per_bf);                 // 32 MiB fp32 -> 128 MiB total

    qkv_rope_kernel<<<dim3(NTOK / 64, F3 / 64), 256, 0, stream>>>(
        x, wq, q_hi, q_lo, k_hi, k_lo, v_th, v_tl);
    attn_kernel<<<dim3(16, BH), 256, 0, stream>>>(
        q_hi, q_lo, k_hi, k_lo, v_th, v_tl, o_ws);
    proj_kernel<<<dim3(NTOK / 64, DMODEL / 64), 256, 0, stream>>>(o_ws, wo, bo, out);
}

// Round 3
// 496.839 us; speedup vs baseline: 2.3457x; 1.7429x over previous
//
#include <hip/hip_runtime.h>
#include <math.h>

#define NH 8
#define HD 64
#define NSEQ 1024
#define DMODEL 512
#define F3 1536
#define NTOK 16384
#define BH 128    // (B*T)*NH = 16*8
#define PITCH 72  // attention LDS pitch (bf16)
#define TP 136    // epilogue transpose pitch (bf16)

typedef __attribute__((ext_vector_type(8))) short bf16x8;
typedef __attribute__((ext_vector_type(4))) float f32x4;
#define MFMA16(a, b, c) __builtin_amdgcn_mfma_f32_16x16x32_bf16(a, b, c, 0, 0, 0)

__device__ __forceinline__ float freq_of(int j) {
    // pi * linspace(1, 128, 16)[j]
    return 3.14159265358979323846f * (1.0f + (float)j * (127.0f / 15.0f));
}
__device__ __forceinline__ unsigned short bf16_hi(float x) {
    unsigned u = __builtin_bit_cast(unsigned, x);
    return (unsigned short)(u >> 16);   // truncation split; residual goes to lo
}
__device__ __forceinline__ float bf16_tofloat(unsigned short h) {
    unsigned u = ((unsigned)h) << 16;
    return __builtin_bit_cast(float, u);
}
__device__ __forceinline__ void gld_lds16(unsigned short* lds_dst, const unsigned short* gsrc) {
    // async global->LDS, 16 B/lane; LDS dest = wave-uniform base + lane*16
    __builtin_amdgcn_global_load_lds(
        (const __attribute__((address_space(1))) unsigned int*)gsrc,
        (__attribute__((address_space(3))) unsigned int*)lds_dst,
        16, 0, 0);
}

// ---------------- Kernel 0: split x -> bf16 hi/lo ----------------
__global__ __launch_bounds__(256) void split_kernel(
        const float* __restrict__ src, unsigned short* __restrict__ hi,
        unsigned short* __restrict__ lo) {
    const int i = blockIdx.x * 256 + threadIdx.x;   // one float4 per thread
    const float4 v = ((const float4*)src)[i];
    ushort4 h, l;
    h.x = bf16_hi(v.x); l.x = bf16_hi(v.x - bf16_tofloat(h.x));
    h.y = bf16_hi(v.y); l.y = bf16_hi(v.y - bf16_tofloat(h.y));
    h.z = bf16_hi(v.z); l.z = bf16_hi(v.z - bf16_tofloat(h.z));
    h.w = bf16_hi(v.w); l.w = bf16_hi(v.w - bf16_tofloat(h.w));
    ((ushort4*)hi)[i] = h;
    ((ushort4*)lo)[i] = l;
}

// ---------------- Kernel 1: QKV GEMM (split-bf16 MFMA) + RoPE ----------------
// C[m][f] = sum_k X[m][k] * Wq[f][k].  128x128 tile, BK=32, 4 waves (2x2 of 64x64).
// A (x hi/lo) staged via global_load_lds (unpadded [128][32]); B (wq fp32) staged
// via float4 load + in-reg split + ds_write. Epilogue: rope (LDS sincos tables),
// split, coalesced 16-B stores through LDS transpose buffer.
__global__ __launch_bounds__(256) void qkv_mfma_kernel(
        const unsigned short* __restrict__ x_hi, const unsigned short* __restrict__ x_lo,
        const float* __restrict__ wq,
        unsigned short* __restrict__ q_hi, unsigned short* __restrict__ q_lo,
        unsigned short* __restrict__ k_hi, unsigned short* __restrict__ k_lo,
        unsigned short* __restrict__ v_th, unsigned short* __restrict__ v_tl) {
    __shared__ __align__(16) char lds[34816 + 4608];
    unsigned short* Ah = (unsigned short*)(lds);
    unsigned short* Al = (unsigned short*)(lds + 8192);
    unsigned short* Bh = (unsigned short*)(lds + 16384);
    unsigned short* Bl = (unsigned short*)(lds + 24576);
    unsigned short* T  = (unsigned short*)(lds);          // 128 x TP (reused after GEMM)
    float* t_cy = (float*)(lds + 34816);                  // [4][16]
    float* t_sy = t_cy + 64;
    float* t_cx = t_sy + 64;                              // [32][16]
    float* t_sx = t_cx + 512;

    const int m0 = blockIdx.x * 128;
    const int f0 = blockIdx.y * 128;
    const int t = threadIdx.x;
    const int w = t >> 6, lane = t & 63, l15 = lane & 15, quad = lane >> 4;
    const int mw = (w & 1) * 64, nw = (w >> 1) * 64;
    const int sel = f0 >> 9;                // 0=q,1=k,2=v
    const int bt = m0 >> 10;
    const int n0 = m0 & 1023;

    if (sel != 2) {
        for (int idx = t; idx < 576; idx += 256) {
            if (idx < 64) {
                const int yi = idx >> 4, j = idx & 15;
                const float pos = -1.0f + (float)((n0 >> 5) + yi) * (2.0f / 31.0f);
                float sv, cv; sincosf(pos * freq_of(j), &sv, &cv);
                t_sy[idx] = sv; t_cy[idx] = cv;
            } else {
                const int k2 = idx - 64, xi = k2 >> 4, j = k2 & 15;
                const float pos = -1.0f + (float)xi * (2.0f / 31.0f);
                float sv, cv; sincosf(pos * freq_of(j), &sv, &cv);
                t_sx[k2] = sv; t_cx[k2] = cv;
            }
        }
    }

    f32x4 acc[4][4];
    #pragma unroll
    for (int mt = 0; mt < 4; mt++)
        #pragma unroll
        for (int nt = 0; nt < 4; nt++) acc[mt][nt] = (f32x4){0.f, 0.f, 0.f, 0.f};

    for (int kt = 0; kt < 16; kt++) {
        const int k0 = kt * 32;
        __syncthreads();
        // ---- async A stage: 16 instrs of 1024B (4 per wave) ----
        #pragma unroll
        for (int ii = 0; ii < 4; ii++) {
            const int idx = w * 4 + ii;
            const int chunk = idx & 7;
            const unsigned short* src = (idx < 8) ? x_hi : x_lo;
            unsigned short* dbuf = (idx < 8) ? Ah : Al;
            const unsigned short* g = src +
                (size_t)(m0 + chunk * 16 + (lane >> 2)) * DMODEL + k0 + (lane & 3) * 8;
            gld_lds16(dbuf + chunk * 512, g);
        }
        // ---- B stage: fp32 -> split -> LDS ----
        #pragma unroll
        for (int p = 0; p < 4; p++) {
            const int idx = p * 256 + t;
            const int r = idx >> 3, c4 = (idx & 7) * 4;
            const float4 wv = *(const float4*)&wq[(size_t)(f0 + r) * DMODEL + k0 + c4];
            ushort4 hv, lv;
            hv.x = bf16_hi(wv.x); lv.x = bf16_hi(wv.x - bf16_tofloat(hv.x));
            hv.y = bf16_hi(wv.y); lv.y = bf16_hi(wv.y - bf16_tofloat(hv.y));
            hv.z = bf16_hi(wv.z); lv.z = bf16_hi(wv.z - bf16_tofloat(hv.z));
            hv.w = bf16_hi(wv.w); lv.w = bf16_hi(wv.w - bf16_tofloat(hv.w));
            *(ushort4*)&Bh[r * 32 + c4] = hv;
            *(ushort4*)&Bl[r * 32 + c4] = lv;
        }
        __syncthreads();
        // ---- fragments + 48 MFMA ----
        bf16x8 afh[4], afl[4], bfh[4], bfl[4];
        #pragma unroll
        for (int mt = 0; mt < 4; mt++) {
            const int off = (mw + mt * 16 + l15) * 32 + quad * 8;
            afh[mt] = *(const bf16x8*)&Ah[off];
            afl[mt] = *(const bf16x8*)&Al[off];
        }
        #pragma unroll
        for (int nt = 0; nt < 4; nt++) {
            const int off = (nw + nt * 16 + l15) * 32 + quad * 8;
            bfh[nt] = *(const bf16x8*)&Bh[off];
            bfl[nt] = *(const bf16x8*)&Bl[off];
        }
        #pragma unroll
        for (int mt = 0; mt < 4; mt++)
            #pragma unroll
            for (int nt = 0; nt < 4; nt++) {
                acc[mt][nt] = MFMA16(afh[mt], bfh[nt], acc[mt][nt]);
                acc[mt][nt] = MFMA16(afh[mt], bfl[nt], acc[mt][nt]);
                acc[mt][nt] = MFMA16(afl[mt], bfh[nt], acc[mt][nt]);
            }
    }
    __syncthreads();

    // ---- rope in place (q,k) ----
    if (sel != 2) {
        #pragma unroll
        for (int mt = 0; mt < 4; mt++)
            #pragma unroll
            for (int nt = 0; nt < 4; nt++)
                #pragma unroll
                for (int rr = 0; rr < 4; rr++) {
                    const int ml = mw + mt * 16 + quad * 4 + rr;
                    const int dd = (nw + nt * 16 + l15) & 63;
                    const int j0 = (dd & 31) >> 1;
                    float c, s;
                    if (dd < 32) { c = t_cy[(ml >> 5) * 16 + j0]; s = t_sy[(ml >> 5) * 16 + j0]; }
                    else         { c = t_cx[(ml & 31) * 16 + j0]; s = t_sx[(ml & 31) * 16 + j0]; }
                    const float v = acc[mt][nt][rr];
                    const float pv = __shfl_xor(v, 1);
                    acc[mt][nt][rr] = (l15 & 1) ? (v * c + pv * s) : (v * c - pv * s);
                }
    }

    // ---- two passes (hi, lo) through transpose buffer, 16-B stores ----
    for (int pass = 0; pass < 2; pass++) {
        #pragma unroll
        for (int mt = 0; mt < 4; mt++)
            #pragma unroll
            for (int nt = 0; nt < 4; nt++)
                #pragma unroll
                for (int rr = 0; rr < 4; rr++) {
                    const int ml = mw + mt * 16 + quad * 4 + rr;
                    const int fl = nw + nt * 16 + l15;
                    const float v = acc[mt][nt][rr];
                    const unsigned short h = bf16_hi(v);
                    const unsigned short val = (pass == 0) ? h : bf16_hi(v - bf16_tofloat(h));
                    if (sel == 2) T[fl * TP + ml] = val;   // v: [f][n] rows
                    else          T[ml * TP + fl] = val;   // q/k: [n][f] rows
                }
        __syncthreads();
        if (sel == 2) {
            unsigned short* dst = (pass == 0) ? v_th : v_tl;
            #pragma unroll
            for (int p = 0; p < 8; p++) {
                const int idx = p * 256 + t;
                const int fl = idx >> 4, g = (idx & 15) * 8;
                const int head = ((f0 + fl) >> 6) & 7;
                unsigned short* gp = dst +
                    ((size_t)(bt * NH + head) * HD + (fl & 63)) * NSEQ + n0 + g;
                *(uint4*)gp = *(const uint4*)&T[fl * TP + g];
            }
        } else {
            unsigned short* dst = (sel == 0) ? ((pass == 0) ? q_hi : q_lo)
                                             : ((pass == 0) ? k_hi : k_lo);
            #pragma unroll
            for (int p = 0; p < 8; p++) {
                const int idx = p * 256 + t;
                const int ml = idx >> 4, g = (idx & 15) * 8;
                const int head = ((f0 + g) >> 6) & 7;
                unsigned short* gp = dst +
                    ((size_t)(bt * NH + head) * NSEQ + n0 + ml) * HD + (g & 63);
                *(uint4*)gp = *(const uint4*)&T[ml * TP + g];
            }
        }
        __syncthreads();
    }
}

// ---------------- Kernel 2: flash attention, split-bf16 MFMA ----------------
__global__ __launch_bounds__(256) void attn_kernel(
        const unsigned short* __restrict__ q_hi, const unsigned short* __restrict__ q_lo,
        const unsigned short* __restrict__ k_hi, const unsigned short* __restrict__ k_lo,
        const unsigned short* __restrict__ v_th, const unsigned short* __restrict__ v_tl,
        unsigned short* __restrict__ o_hi, unsigned short* __restrict__ o_lo) {
    __shared__ unsigned short KPh[64 * PITCH];
    __shared__ unsigned short KPl[64 * PITCH];
    __shared__ unsigned short Vsh[64 * PITCH];
    __shared__ unsigned short Vsl[64 * PITCH];

    const int qt = blockIdx.x;
    const int bh = blockIdx.y;
    const int t = threadIdx.x;
    const int w = t >> 6;
    const int lane = t & 63;
    const int l15 = lane & 15;
    const int quad = lane >> 4;
    const float scale = 0.125f;

    const size_t bh_nd = (size_t)bh * NSEQ * HD;
    const size_t bh_dn = (size_t)bh * HD * NSEQ;

    #pragma unroll
    for (int p = 0; p < 2; p++) {
        const int cc = t + p * 256;
        const int r = cc >> 3, off8 = (cc & 7) * 8;
        const size_t g = bh_nd + (size_t)(qt * 64 + r) * HD + off8;
        *(uint4*)&KPh[r * PITCH + off8] = *(const uint4*)(q_hi + g);
        *(uint4*)&KPl[r * PITCH + off8] = *(const uint4*)(q_lo + g);
    }
    __syncthreads();
    bf16x8 qfh[2], qfl[2];
    {
        const int r = w * 16 + l15;
        #pragma unroll
        for (int ks = 0; ks < 2; ks++) {
            qfh[ks] = *(const bf16x8*)&KPh[r * PITCH + ks * 32 + quad * 8];
            qfl[ks] = *(const bf16x8*)&KPl[r * PITCH + ks * 32 + quad * 8];
        }
    }

    f32x4 o_acc[4];
    #pragma unroll
    for (int dt = 0; dt < 4; dt++) o_acc[dt] = (f32x4){0.f, 0.f, 0.f, 0.f};
    float m_i[4] = {-1e30f, -1e30f, -1e30f, -1e30f};
    float l_i[4] = {0.f, 0.f, 0.f, 0.f};

    for (int kt = 0; kt < 16; kt++) {
        __syncthreads();
        #pragma unroll
        for (int p = 0; p < 2; p++) {
            const int cc = t + p * 256;
            const int r = cc >> 3, off8 = (cc & 7) * 8;
            const size_t gk = bh_nd + (size_t)(kt * 64 + r) * HD + off8;
            *(uint4*)&KPh[r * PITCH + off8] = *(const uint4*)(k_hi + gk);
            *(uint4*)&KPl[r * PITCH + off8] = *(const uint4*)(k_lo + gk);
            const size_t gv = bh_dn + (size_t)r * NSEQ + kt * 64 + off8;
            *(uint4*)&Vsh[r * PITCH + off8] = *(const uint4*)(v_th + gv);
            *(uint4*)&Vsl[r * PITCH + off8] = *(const uint4*)(v_tl + gv);
        }
        __syncthreads();

        f32x4 s[4];
        #pragma unroll
        for (int nt = 0; nt < 4; nt++) {
            s[nt] = (f32x4){0.f, 0.f, 0.f, 0.f};
            #pragma unroll
            for (int ks = 0; ks < 2; ks++) {
                const int boff = (nt * 16 + l15) * PITCH + ks * 32 + quad * 8;
                const bf16x8 kbh = *(const bf16x8*)&KPh[boff];
                const bf16x8 kbl = *(const bf16x8*)&KPl[boff];
                s[nt] = MFMA16(qfh[ks], kbh, s[nt]);
                s[nt] = MFMA16(qfh[ks], kbl, s[nt]);
                s[nt] = MFMA16(qfl[ks], kbh, s[nt]);
            }
        }
        __syncthreads();

        #pragma unroll
        for (int r = 0; r < 4; r++) {
            float v0 = s[0][r] * scale, v1 = s[1][r] * scale;
            float v2 = s[2][r] * scale, v3 = s[3][r] * scale;
            float mt = fmaxf(fmaxf(v0, v1), fmaxf(v2, v3));
            #pragma unroll
            for (int off = 1; off < 16; off <<= 1) mt = fmaxf(mt, __shfl_xor(mt, off));
            const float mnew = fmaxf(m_i[r], mt);
            const float alpha = __expf(m_i[r] - mnew);
            const float e0 = __expf(v0 - mnew), e1 = __expf(v1 - mnew);
            const float e2 = __expf(v2 - mnew), e3 = __expf(v3 - mnew);
            float ls = e0 + e1 + e2 + e3;
            #pragma unroll
            for (int off = 1; off < 16; off <<= 1) ls += __shfl_xor(ls, off);
            l_i[r] = l_i[r] * alpha + ls;
            m_i[r] = mnew;
            #pragma unroll
            for (int dt = 0; dt < 4; dt++) o_acc[dt][r] *= alpha;
            const int prow = w * 16 + quad * 4 + r;
            const float ev[4] = {e0, e1, e2, e3};
            #pragma unroll
            for (int nt = 0; nt < 4; nt++) {
                const int col = nt * 16 + l15;
                const unsigned short hb = bf16_hi(ev[nt]);
                KPh[prow * PITCH + col] = hb;
                KPl[prow * PITCH + col] = bf16_hi(ev[nt] - bf16_tofloat(hb));
            }
        }
        __syncthreads();

        bf16x8 pfh[2], pfl[2];
        {
            const int pr = w * 16 + l15;
            #pragma unroll
            for (int ks = 0; ks < 2; ks++) {
                pfh[ks] = *(const bf16x8*)&KPh[pr * PITCH + ks * 32 + quad * 8];
                pfl[ks] = *(const bf16x8*)&KPl[pr * PITCH + ks * 32 + quad * 8];
            }
        }
        #pragma unroll
        for (int dt = 0; dt < 4; dt++) {
            #pragma unroll
            for (int ks = 0; ks < 2; ks++) {
                const int voff = (dt * 16 + l15) * PITCH + ks * 32 + quad * 8;
                const bf16x8 vbh = *(const bf16x8*)&Vsh[voff];
                const bf16x8 vbl = *(const bf16x8*)&Vsl[voff];
                o_acc[dt] = MFMA16(pfh[ks], vbh, o_acc[dt]);
                o_acc[dt] = MFMA16(pfh[ks], vbl, o_acc[dt]);
                o_acc[dt] = MFMA16(pfl[ks], vbh, o_acc[dt]);
            }
        }
    }

    // epilogue: normalize, split to bf16 hi/lo in [m][f] layout for proj
    const int btq = bh >> 3, head = bh & 7;
    #pragma unroll
    for (int r = 0; r < 4; r++) {
        const float inv = 1.0f / l_i[r];
        const int row = qt * 64 + w * 16 + quad * 4 + r;
        #pragma unroll
        for (int dt = 0; dt < 4; dt++) {
            const float val = o_acc[dt][r] * inv;
            const unsigned short h = bf16_hi(val);
            const size_t off = ((size_t)(btq * NSEQ + row)) * DMODEL + head * HD + dt * 16 + l15;
            o_hi[off] = h;
            o_lo[off] = bf16_hi(val - bf16_tofloat(h));
        }
    }
}

// ---------------- Kernel 3: output projection (split-bf16 MFMA) ----------------
__global__ __launch_bounds__(256) void proj_mfma_kernel(
        const unsigned short* __restrict__ o_hi, const unsigned short* __restrict__ o_lo,
        const float* __restrict__ w_out, const float* __restrict__ b_out,
        float* __restrict__ out) {
    __shared__ __align__(16) char lds[32768];
    unsigned short* Ah = (unsigned short*)(lds);
    unsigned short* Al = (unsigned short*)(lds + 8192);
    unsigned short* Bh = (unsigned short*)(lds + 16384);
    unsigned short* Bl = (unsigned short*)(lds + 24576);

    const int m0 = blockIdx.x * 128;
    const int f0 = blockIdx.y * 128;
    const int t = threadIdx.x;
    const int w = t >> 6, lane = t & 63, l15 = lane & 15, quad = lane >> 4;
    const int mw = (w & 1) * 64, nw = (w >> 1) * 64;

    f32x4 acc[4][4];
    #pragma unroll
    for (int mt = 0; mt < 4; mt++)
        #pragma unroll
        for (int nt = 0; nt < 4; nt++) acc[mt][nt] = (f32x4){0.f, 0.f, 0.f, 0.f};

    for (int kt = 0; kt < 16; kt++) {
        const int k0 = kt * 32;
        __syncthreads();
        #pragma unroll
        for (int ii = 0; ii < 4; ii++) {
            const int idx = w * 4 + ii;
            const int chunk = idx & 7;
            const unsigned short* src = (idx < 8) ? o_hi : o_lo;
            unsigned short* dbuf = (idx < 8) ? Ah : Al;
            const unsigned short* g = src +
                (size_t)(m0 + chunk * 16 + (lane >> 2)) * DMODEL + k0 + (lane & 3) * 8;
            gld_lds16(dbuf + chunk * 512, g);
        }
        #pragma unroll
        for (int p = 0; p < 4; p++) {
            const int idx = p * 256 + t;
            const int r = idx >> 3, c4 = (idx & 7) * 4;
            const float4 wv = *(const float4*)&w_out[(size_t)(f0 + r) * DMODEL + k0 + c4];
            ushort4 hv, lv;
            hv.x = bf16_hi(wv.x); lv.x = bf16_hi(wv.x - bf16_tofloat(hv.x));
            hv.y = bf16_hi(wv.y); lv.y = bf16_hi(wv.y - bf16_tofloat(hv.y));
            hv.z = bf16_hi(wv.z); lv.z = bf16_hi(wv.z - bf16_tofloat(hv.z));
            hv.w = bf16_hi(wv.w); lv.w = bf16_hi(wv.w - bf16_tofloat(hv.w));
            *(ushort4*)&Bh[r * 32 + c4] = hv;
            *(ushort4*)&Bl[r * 32 + c4] = lv;
        }
        __syncthreads();
        bf16x8 afh[4], afl[4], bfh[4], bfl[4];
        #pragma unroll
        for (int mt = 0; mt < 4; mt++) {
            const int off = (mw + mt * 16 + l15) * 32 + quad * 8;
            afh[mt] = *(const bf16x8*)&Ah[off];
            afl[mt] = *(const bf16x8*)&Al[off];
        }
        #pragma unroll
        for (int nt = 0; nt < 4; nt++) {
            const int off = (nw + nt * 16 + l15) * 32 + quad * 8;
            bfh[nt] = *(const bf16x8*)&Bh[off];
            bfl[nt] = *(const bf16x8*)&Bl[off];
        }
        #pragma unroll
        for (int mt = 0; mt < 4; mt++)
            #pragma unroll
            for (int nt = 0; nt < 4; nt++) {
                acc[mt][nt] = MFMA16(afh[mt], bfh[nt], acc[mt][nt]);
                acc[mt][nt] = MFMA16(afh[mt], bfl[nt], acc[mt][nt]);
                acc[mt][nt] = MFMA16(afl[mt], bfh[nt], acc[mt][nt]);
            }
    }

    float bias_v[4];
    #pragma unroll
    for (int nt = 0; nt < 4; nt++) bias_v[nt] = b_out[f0 + nw + nt * 16 + l15];
    #pragma unroll
    for (int mt = 0; mt < 4; mt++)
        #pragma unroll
        for (int nt = 0; nt < 4; nt++)
            #pragma unroll
            for (int rr = 0; rr < 4; rr++) {
                const int m = m0 + mw + mt * 16 + quad * 4 + rr;
                out[(size_t)m * DMODEL + f0 + nw + nt * 16 + l15] =
                    acc[mt][nt][rr] + bias_v[nt];
            }
}

extern "C" void kernel_launch(void* const* d_in, const int* in_sizes, int n_in,
                              void* d_out, int out_size, void* d_ws, size_t ws_size,
                              hipStream_t stream) {
    const float* x  = (const float*)d_in[0];
    const float* wq = (const float*)d_in[1];
    const float* wo = (const float*)d_in[2];
    const float* bo = (const float*)d_in[3];
    float* out = (float*)d_out;

    const size_t per = (size_t)BH * NSEQ * HD;   // 8,388,608 elements
    unsigned short* x_hi = (unsigned short*)d_ws;        // 16 MiB, reused as o_hi
    unsigned short* x_lo = x_hi + per;                   // 16 MiB, reused as o_lo
    unsigned short* q_hi = x_lo + per;
    unsigned short* q_lo = q_hi + per;
    unsigned short* k_hi = q_lo + per;
    unsigned short* k_lo = k_hi + per;
    unsigned short* v_th = k_lo + per;
    unsigned short* v_tl = v_th + per;                   // total 128 MiB
    unsigned short* o_hi = x_hi;   // x dead after qkv GEMM
    unsigned short* o_lo = x_lo;

    split_kernel<<<dim3((int)(per / 1024)), 256, 0, stream>>>(x, x_hi, x_lo);
    qkv_mfma_kernel<<<dim3(NTOK / 128, F3 / 128), 256, 0, stream>>>(
        x_hi, x_lo, wq, q_hi, q_lo, k_hi, k_lo, v_th, v_tl);
    attn_kernel<<<dim3(16, BH), 256, 0, stream>>>(
        q_hi, q_lo, k_hi, k_lo, v_th, v_tl, o_hi, o_lo);
    proj_mfma_kernel<<<dim3(NTOK / 128, DMODEL / 128), 256, 0, stream>>>(
        o_hi, o_lo, wo, bo, out);
}

// Round 4
// 454.707 us; speedup vs baseline: 2.5631x; 1.0927x over previous
//
#include <hip/hip_runtime.h>
#include <math.h>

#define NH 8
#define HD 64
#define NSEQ 1024
#define DMODEL 512
#define F3 1536
#define NTOK 16384
#define BH 128    // (B*T)*NH = 16*8
#define KVP 72    // K/V LDS pitch (bf16)
#define TP 136    // qkv epilogue transpose pitch (bf16)
#define QSCALE 0.1803368867f  // 0.125 * log2(e), folded into q; p = exp2(s')

typedef __attribute__((ext_vector_type(8))) short bf16x8;
typedef __attribute__((ext_vector_type(4))) float f32x4;
#define MFMA16(a, b, c) __builtin_amdgcn_mfma_f32_16x16x32_bf16(a, b, c, 0, 0, 0)

__device__ __forceinline__ float freq_of(int j) {
    // pi * linspace(1, 128, 16)[j]
    return 3.14159265358979323846f * (1.0f + (float)j * (127.0f / 15.0f));
}
__device__ __forceinline__ unsigned short bf16_hi(float x) {
    unsigned u = __builtin_bit_cast(unsigned, x);
    return (unsigned short)(u >> 16);   // truncation split; residual goes to lo
}
__device__ __forceinline__ unsigned short bf16_rtn(float x) {
    unsigned u = __builtin_bit_cast(unsigned, x);
    return (unsigned short)((u + 0x7FFF + ((u >> 16) & 1)) >> 16);  // round-nearest-even
}
__device__ __forceinline__ float bf16_tofloat(unsigned short h) {
    unsigned u = ((unsigned)h) << 16;
    return __builtin_bit_cast(float, u);
}
__device__ __forceinline__ void gld_lds16(unsigned short* lds_dst, const unsigned short* gsrc) {
    __builtin_amdgcn_global_load_lds(
        (const __attribute__((address_space(1))) unsigned int*)gsrc,
        (__attribute__((address_space(3))) unsigned int*)lds_dst,
        16, 0, 0);
}

// ---------------- Kernel 0: split x -> bf16 hi/lo ----------------
__global__ __launch_bounds__(256) void split_kernel(
        const float* __restrict__ src, unsigned short* __restrict__ hi,
        unsigned short* __restrict__ lo) {
    const int i = blockIdx.x * 256 + threadIdx.x;
    const float4 v = ((const float4*)src)[i];
    ushort4 h, l;
    h.x = bf16_hi(v.x); l.x = bf16_hi(v.x - bf16_tofloat(h.x));
    h.y = bf16_hi(v.y); l.y = bf16_hi(v.y - bf16_tofloat(h.y));
    h.z = bf16_hi(v.z); l.z = bf16_hi(v.z - bf16_tofloat(h.z));
    h.w = bf16_hi(v.w); l.w = bf16_hi(v.w - bf16_tofloat(h.w));
    ((ushort4*)hi)[i] = h;
    ((ushort4*)lo)[i] = l;
}

// ---------------- Kernel 1: QKV GEMM (split-bf16 MFMA) + RoPE ----------------
__global__ __launch_bounds__(256) void qkv_mfma_kernel(
        const unsigned short* __restrict__ x_hi, const unsigned short* __restrict__ x_lo,
        const float* __restrict__ wq,
        unsigned short* __restrict__ q_hi, unsigned short* __restrict__ q_lo,
        unsigned short* __restrict__ k_hi, unsigned short* __restrict__ k_lo,
        unsigned short* __restrict__ v_th, unsigned short* __restrict__ v_tl) {
    __shared__ __align__(16) char lds[34816 + 4608];
    unsigned short* Ah = (unsigned short*)(lds);
    unsigned short* Al = (unsigned short*)(lds + 8192);
    unsigned short* Bh = (unsigned short*)(lds + 16384);
    unsigned short* Bl = (unsigned short*)(lds + 24576);
    unsigned short* T  = (unsigned short*)(lds);
    float* t_cy = (float*)(lds + 34816);
    float* t_sy = t_cy + 64;
    float* t_cx = t_sy + 64;
    float* t_sx = t_cx + 512;

    const int m0 = blockIdx.x * 128;
    const int f0 = blockIdx.y * 128;
    const int t = threadIdx.x;
    const int w = t >> 6, lane = t & 63, l15 = lane & 15, quad = lane >> 4;
    const int mw = (w & 1) * 64, nw = (w >> 1) * 64;
    const int sel = f0 >> 9;                // 0=q,1=k,2=v
    const int bt = m0 >> 10;
    const int n0 = m0 & 1023;

    if (sel != 2) {
        for (int idx = t; idx < 576; idx += 256) {
            if (idx < 64) {
                const int yi = idx >> 4, j = idx & 15;
                const float pos = -1.0f + (float)((n0 >> 5) + yi) * (2.0f / 31.0f);
                float sv, cv; sincosf(pos * freq_of(j), &sv, &cv);
                t_sy[idx] = sv; t_cy[idx] = cv;
            } else {
                const int k2 = idx - 64, xi = k2 >> 4, j = k2 & 15;
                const float pos = -1.0f + (float)xi * (2.0f / 31.0f);
                float sv, cv; sincosf(pos * freq_of(j), &sv, &cv);
                t_sx[k2] = sv; t_cx[k2] = cv;
            }
        }
    }

    f32x4 acc[4][4];
    #pragma unroll
    for (int mt = 0; mt < 4; mt++)
        #pragma unroll
        for (int nt = 0; nt < 4; nt++) acc[mt][nt] = (f32x4){0.f, 0.f, 0.f, 0.f};

    for (int kt = 0; kt < 16; kt++) {
        const int k0 = kt * 32;
        __syncthreads();
        #pragma unroll
        for (int ii = 0; ii < 4; ii++) {
            const int idx = w * 4 + ii;
            const int chunk = idx & 7;
            const unsigned short* src = (idx < 8) ? x_hi : x_lo;
            unsigned short* dbuf = (idx < 8) ? Ah : Al;
            const unsigned short* g = src +
                (size_t)(m0 + chunk * 16 + (lane >> 2)) * DMODEL + k0 + (lane & 3) * 8;
            gld_lds16(dbuf + chunk * 512, g);
        }
        #pragma unroll
        for (int p = 0; p < 4; p++) {
            const int idx = p * 256 + t;
            const int r = idx >> 3, c4 = (idx & 7) * 4;
            const float4 wv = *(const float4*)&wq[(size_t)(f0 + r) * DMODEL + k0 + c4];
            ushort4 hv, lv;
            hv.x = bf16_hi(wv.x); lv.x = bf16_hi(wv.x - bf16_tofloat(hv.x));
            hv.y = bf16_hi(wv.y); lv.y = bf16_hi(wv.y - bf16_tofloat(hv.y));
            hv.z = bf16_hi(wv.z); lv.z = bf16_hi(wv.z - bf16_tofloat(hv.z));
            hv.w = bf16_hi(wv.w); lv.w = bf16_hi(wv.w - bf16_tofloat(hv.w));
            *(ushort4*)&Bh[r * 32 + c4] = hv;
            *(ushort4*)&Bl[r * 32 + c4] = lv;
        }
        __syncthreads();
        bf16x8 afh[4], afl[4], bfh[4], bfl[4];
        #pragma unroll
        for (int mt = 0; mt < 4; mt++) {
            const int off = (mw + mt * 16 + l15) * 32 + quad * 8;
            afh[mt] = *(const bf16x8*)&Ah[off];
            afl[mt] = *(const bf16x8*)&Al[off];
        }
        #pragma unroll
        for (int nt = 0; nt < 4; nt++) {
            const int off = (nw + nt * 16 + l15) * 32 + quad * 8;
            bfh[nt] = *(const bf16x8*)&Bh[off];
            bfl[nt] = *(const bf16x8*)&Bl[off];
        }
        #pragma unroll
        for (int mt = 0; mt < 4; mt++)
            #pragma unroll
            for (int nt = 0; nt < 4; nt++) {
                acc[mt][nt] = MFMA16(afh[mt], bfh[nt], acc[mt][nt]);
                acc[mt][nt] = MFMA16(afh[mt], bfl[nt], acc[mt][nt]);
                acc[mt][nt] = MFMA16(afl[mt], bfh[nt], acc[mt][nt]);
            }
    }
    __syncthreads();

    // rope in place (q,k); q additionally scaled by QSCALE so attn uses exp2
    if (sel != 2) {
        const float post = (sel == 0) ? QSCALE : 1.0f;
        #pragma unroll
        for (int mt = 0; mt < 4; mt++)
            #pragma unroll
            for (int nt = 0; nt < 4; nt++)
                #pragma unroll
                for (int rr = 0; rr < 4; rr++) {
                    const int ml = mw + mt * 16 + quad * 4 + rr;
                    const int dd = (nw + nt * 16 + l15) & 63;
                    const int j0 = (dd & 31) >> 1;
                    float c, s;
                    if (dd < 32) { c = t_cy[(ml >> 5) * 16 + j0]; s = t_sy[(ml >> 5) * 16 + j0]; }
                    else         { c = t_cx[(ml & 31) * 16 + j0]; s = t_sx[(ml & 31) * 16 + j0]; }
                    const float v = acc[mt][nt][rr];
                    const float pv = __shfl_xor(v, 1);
                    acc[mt][nt][rr] = ((l15 & 1) ? (v * c + pv * s) : (v * c - pv * s)) * post;
                }
    }

    for (int pass = 0; pass < 2; pass++) {
        #pragma unroll
        for (int mt = 0; mt < 4; mt++)
            #pragma unroll
            for (int nt = 0; nt < 4; nt++)
                #pragma unroll
                for (int rr = 0; rr < 4; rr++) {
                    const int ml = mw + mt * 16 + quad * 4 + rr;
                    const int fl = nw + nt * 16 + l15;
                    const float v = acc[mt][nt][rr];
                    const unsigned short h = bf16_hi(v);
                    const unsigned short val = (pass == 0) ? h : bf16_hi(v - bf16_tofloat(h));
                    if (sel == 2) T[fl * TP + ml] = val;
                    else          T[ml * TP + fl] = val;
                }
        __syncthreads();
        if (sel == 2) {
            unsigned short* dst = (pass == 0) ? v_th : v_tl;
            #pragma unroll
            for (int p = 0; p < 8; p++) {
                const int idx = p * 256 + t;
                const int fl = idx >> 4, g = (idx & 15) * 8;
                const int head = ((f0 + fl) >> 6) & 7;
                unsigned short* gp = dst +
                    ((size_t)(bt * NH + head) * HD + (fl & 63)) * NSEQ + n0 + g;
                *(uint4*)gp = *(const uint4*)&T[fl * TP + g];
            }
        } else {
            unsigned short* dst = (sel == 0) ? ((pass == 0) ? q_hi : q_lo)
                                             : ((pass == 0) ? k_hi : k_lo);
            #pragma unroll
            for (int p = 0; p < 8; p++) {
                const int idx = p * 256 + t;
                const int ml = idx >> 4, g = (idx & 15) * 8;
                const int head = ((f0 + g) >> 6) & 7;
                unsigned short* gp = dst +
                    ((size_t)(bt * NH + head) * NSEQ + n0 + ml) * HD + (g & 63);
                *(uint4*)gp = *(const uint4*)&T[ml * TP + g];
            }
        }
        __syncthreads();
    }
}

// ---------------- Kernel 2: flash attention, no-max exp2 softmax ----------------
// Grid (8,128): 128 q rows/block, 4 waves x 2 m-frags (32 rows/wave).
// p = exp2(s') directly (QSCALE folded into q; scores provably bounded).
// Row-sum l via MFMA with register all-ones B operand. P is wave-private
// (XOR-swizzled [128][64] buffer) -> no barrier between P write and PV read.
__global__ __launch_bounds__(256, 3) void attn_kernel(
        const unsigned short* __restrict__ q_hi, const unsigned short* __restrict__ q_lo,
        const unsigned short* __restrict__ k_hi, const unsigned short* __restrict__ k_lo,
        const unsigned short* __restrict__ v_th, const unsigned short* __restrict__ v_tl,
        unsigned short* __restrict__ o_hi, unsigned short* __restrict__ o_lo) {
    __shared__ unsigned short Ks[128 * KVP];  // rows 0..63: K_hi, 64..127: K_lo
    __shared__ unsigned short Vs[128 * KVP];  // rows 0..63: V^T_hi, 64..127: V^T_lo
    __shared__ unsigned short Ps[128 * 64];   // P, xor-swizzled cols, wave-private rows

    const int qt = blockIdx.x;     // 0..7
    const int bh = blockIdx.y;     // 0..127
    const int t = threadIdx.x;
    const int w = t >> 6;
    const int lane = t & 63;
    const int l15 = lane & 15;
    const int quad = lane >> 4;

    const size_t bh_nd = (size_t)bh * NSEQ * HD;
    const size_t bh_dn = (size_t)bh * HD * NSEQ;

    // Q fragments straight from global (once per block)
    bf16x8 qfh[2][2], qfl[2][2];
    #pragma unroll
    for (int mf = 0; mf < 2; mf++) {
        const size_t rbase = bh_nd + (size_t)(qt * 128 + w * 32 + mf * 16 + l15) * HD;
        #pragma unroll
        for (int ks = 0; ks < 2; ks++) {
            qfh[mf][ks] = *(const bf16x8*)(q_hi + rbase + ks * 32 + quad * 8);
            qfl[mf][ks] = *(const bf16x8*)(q_lo + rbase + ks * 32 + quad * 8);
        }
    }

    const bf16x8 ones = {(short)0x3F80, (short)0x3F80, (short)0x3F80, (short)0x3F80,
                         (short)0x3F80, (short)0x3F80, (short)0x3F80, (short)0x3F80};

    f32x4 o_acc[2][4], l_acc[2];
    #pragma unroll
    for (int mf = 0; mf < 2; mf++) {
        l_acc[mf] = (f32x4){0.f, 0.f, 0.f, 0.f};
        #pragma unroll
        for (int dt = 0; dt < 4; dt++) o_acc[mf][dt] = (f32x4){0.f, 0.f, 0.f, 0.f};
    }

    for (int kt = 0; kt < 16; kt++) {
        __syncthreads();   // prior K/V reads complete
        #pragma unroll
        for (int p = 0; p < 2; p++) {
            const int cc = t + p * 256;
            const int r = cc >> 3, off8 = (cc & 7) * 8;
            const size_t gk = bh_nd + (size_t)(kt * 64 + r) * HD + off8;
            *(uint4*)&Ks[r * KVP + off8]        = *(const uint4*)(k_hi + gk);
            *(uint4*)&Ks[(64 + r) * KVP + off8] = *(const uint4*)(k_lo + gk);
            const size_t gv = bh_dn + (size_t)r * NSEQ + kt * 64 + off8;
            *(uint4*)&Vs[r * KVP + off8]        = *(const uint4*)(v_th + gv);
            *(uint4*)&Vs[(64 + r) * KVP + off8] = *(const uint4*)(v_tl + gv);
        }
        __syncthreads();

        // ---- S = Q K^T (hh+hl+lh), p = exp2(s), store P (bf16 RTN, swizzled) ----
        #pragma unroll
        for (int nt = 0; nt < 4; nt++) {
            bf16x8 kh[2], kl[2];
            #pragma unroll
            for (int ks = 0; ks < 2; ks++) {
                const int off = (nt * 16 + l15) * KVP + ks * 32 + quad * 8;
                kh[ks] = *(const bf16x8*)&Ks[off];
                kl[ks] = *(const bf16x8*)&Ks[64 * KVP + off];
            }
            #pragma unroll
            for (int mf = 0; mf < 2; mf++) {
                f32x4 s = (f32x4){0.f, 0.f, 0.f, 0.f};
                #pragma unroll
                for (int ks = 0; ks < 2; ks++) {
                    s = MFMA16(qfh[mf][ks], kh[ks], s);
                    s = MFMA16(qfh[mf][ks], kl[ks], s);
                    s = MFMA16(qfl[mf][ks], kh[ks], s);
                }
                const int prow_b = w * 32 + mf * 16 + quad * 4;
                const int col = nt * 16 + l15;
                #pragma unroll
                for (int r = 0; r < 4; r++) {
                    const int prow = prow_b + r;
                    const float pv = exp2f(s[r]);
                    Ps[prow * 64 + ((((col >> 3) ^ (prow & 7)) << 3) | (col & 7))] =
                        bf16_rtn(pv);
                }
            }
        }

        // ---- O += P V, l += P 1 (P wave-private: no barrier needed) ----
        bf16x8 pf[2][2];
        #pragma unroll
        for (int mf = 0; mf < 2; mf++) {
            const int prow = w * 32 + mf * 16 + l15;
            #pragma unroll
            for (int ks = 0; ks < 2; ks++)
                pf[mf][ks] = *(const bf16x8*)&Ps[prow * 64 +
                                (((ks * 4 + quad) ^ (prow & 7)) << 3)];
            l_acc[mf] = MFMA16(pf[mf][0], ones, l_acc[mf]);
            l_acc[mf] = MFMA16(pf[mf][1], ones, l_acc[mf]);
        }
        #pragma unroll
        for (int dt = 0; dt < 4; dt++) {
            bf16x8 vh[2], vl[2];
            #pragma unroll
            for (int ks = 0; ks < 2; ks++) {
                const int off = (dt * 16 + l15) * KVP + ks * 32 + quad * 8;
                vh[ks] = *(const bf16x8*)&Vs[off];
                vl[ks] = *(const bf16x8*)&Vs[64 * KVP + off];
            }
            #pragma unroll
            for (int mf = 0; mf < 2; mf++) {
                #pragma unroll
                for (int ks = 0; ks < 2; ks++) {
                    o_acc[mf][dt] = MFMA16(pf[mf][ks], vh[ks], o_acc[mf][dt]);
                    o_acc[mf][dt] = MFMA16(pf[mf][ks], vl[ks], o_acc[mf][dt]);
                }
            }
        }
    }

    // ---- epilogue: normalize by l (self-consistent), split bf16 hi/lo for proj ----
    const int btq = bh >> 3, head = bh & 7;
    #pragma unroll
    for (int mf = 0; mf < 2; mf++)
        #pragma unroll
        for (int r = 0; r < 4; r++) {
            const float inv = 1.0f / l_acc[mf][r];
            const int row = qt * 128 + w * 32 + mf * 16 + quad * 4 + r;
            #pragma unroll
            for (int dt = 0; dt < 4; dt++) {
                const float val = o_acc[mf][dt][r] * inv;
                const unsigned short h = bf16_hi(val);
                const size_t off =
                    ((size_t)(btq * NSEQ + row)) * DMODEL + head * HD + dt * 16 + l15;
                o_hi[off] = h;
                o_lo[off] = bf16_hi(val - bf16_tofloat(h));
            }
        }
}

// ---------------- Kernel 3: output projection (split-bf16 MFMA) ----------------
__global__ __launch_bounds__(256) void proj_mfma_kernel(
        const unsigned short* __restrict__ o_hi, const unsigned short* __restrict__ o_lo,
        const float* __restrict__ w_out, const float* __restrict__ b_out,
        float* __restrict__ out) {
    __shared__ __align__(16) char lds[32768];
    unsigned short* Ah = (unsigned short*)(lds);
    unsigned short* Al = (unsigned short*)(lds + 8192);
    unsigned short* Bh = (unsigned short*)(lds + 16384);
    unsigned short* Bl = (unsigned short*)(lds + 24576);

    const int m0 = blockIdx.x * 128;
    const int f0 = blockIdx.y * 128;
    const int t = threadIdx.x;
    const int w = t >> 6, lane = t & 63, l15 = lane & 15, quad = lane >> 4;
    const int mw = (w & 1) * 64, nw = (w >> 1) * 64;

    f32x4 acc[4][4];
    #pragma unroll
    for (int mt = 0; mt < 4; mt++)
        #pragma unroll
        for (int nt = 0; nt < 4; nt++) acc[mt][nt] = (f32x4){0.f, 0.f, 0.f, 0.f};

    for (int kt = 0; kt < 16; kt++) {
        const int k0 = kt * 32;
        __syncthreads();
        #pragma unroll
        for (int ii = 0; ii < 4; ii++) {
            const int idx = w * 4 + ii;
            const int chunk = idx & 7;
            const unsigned short* src = (idx < 8) ? o_hi : o_lo;
            unsigned short* dbuf = (idx < 8) ? Ah : Al;
            const unsigned short* g = src +
                (size_t)(m0 + chunk * 16 + (lane >> 2)) * DMODEL + k0 + (lane & 3) * 8;
            gld_lds16(dbuf + chunk * 512, g);
        }
        #pragma unroll
        for (int p = 0; p < 4; p++) {
            const int idx = p * 256 + t;
            const int r = idx >> 3, c4 = (idx & 7) * 4;
            const float4 wv = *(const float4*)&w_out[(size_t)(f0 + r) * DMODEL + k0 + c4];
            ushort4 hv, lv;
            hv.x = bf16_hi(wv.x); lv.x = bf16_hi(wv.x - bf16_tofloat(hv.x));
            hv.y = bf16_hi(wv.y); lv.y = bf16_hi(wv.y - bf16_tofloat(hv.y));
            hv.z = bf16_hi(wv.z); lv.z = bf16_hi(wv.z - bf16_tofloat(hv.z));
            hv.w = bf16_hi(wv.w); lv.w = bf16_hi(wv.w - bf16_tofloat(hv.w));
            *(ushort4*)&Bh[r * 32 + c4] = hv;
            *(ushort4*)&Bl[r * 32 + c4] = lv;
        }
        __syncthreads();
        bf16x8 afh[4], afl[4], bfh[4], bfl[4];
        #pragma unroll
        for (int mt = 0; mt < 4; mt++) {
            const int off = (mw + mt * 16 + l15) * 32 + quad * 8;
            afh[mt] = *(const bf16x8*)&Ah[off];
            afl[mt] = *(const bf16x8*)&Al[off];
        }
        #pragma unroll
        for (int nt = 0; nt < 4; nt++) {
            const int off = (nw + nt * 16 + l15) * 32 + quad * 8;
            bfh[nt] = *(const bf16x8*)&Bh[off];
            bfl[nt] = *(const bf16x8*)&Bl[off];
        }
        #pragma unroll
        for (int mt = 0; mt < 4; mt++)
            #pragma unroll
            for (int nt = 0; nt < 4; nt++) {
                acc[mt][nt] = MFMA16(afh[mt], bfh[nt], acc[mt][nt]);
                acc[mt][nt] = MFMA16(afh[mt], bfl[nt], acc[mt][nt]);
                acc[mt][nt] = MFMA16(afl[mt], bfh[nt], acc[mt][nt]);
            }
    }

    float bias_v[4];
    #pragma unroll
    for (int nt = 0; nt < 4; nt++) bias_v[nt] = b_out[f0 + nw + nt * 16 + l15];
    #pragma unroll
    for (int mt = 0; mt < 4; mt++)
        #pragma unroll
        for (int nt = 0; nt < 4; nt++)
            #pragma unroll
            for (int rr = 0; rr < 4; rr++) {
                const int m = m0 + mw + mt * 16 + quad * 4 + rr;
                out[(size_t)m * DMODEL + f0 + nw + nt * 16 + l15] =
                    acc[mt][nt][rr] + bias_v[nt];
            }
}

extern "C" void kernel_launch(void* const* d_in, const int* in_sizes, int n_in,
                              void* d_out, int out_size, void* d_ws, size_t ws_size,
                              hipStream_t stream) {
    const float* x  = (const float*)d_in[0];
    const float* wq = (const float*)d_in[1];
    const float* wo = (const float*)d_in[2];
    const float* bo = (const float*)d_in[3];
    float* out = (float*)d_out;

    const size_t per = (size_t)BH * NSEQ * HD;   // 8,388,608 elements
    unsigned short* x_hi = (unsigned short*)d_ws;        // reused as o_hi after qkv
    unsigned short* x_lo = x_hi + per;                   // reused as o_lo
    unsigned short* q_hi = x_lo + per;
    unsigned short* q_lo = q_hi + per;
    unsigned short* k_hi = q_lo + per;
    unsigned short* k_lo = k_hi + per;
    unsigned short* v_th = k_lo + per;
    unsigned short* v_tl = v_th + per;                   // 128 MiB total
    unsigned short* o_hi = x_hi;
    unsigned short* o_lo = x_lo;

    split_kernel<<<dim3((int)(per / 1024)), 256, 0, stream>>>(x, x_hi, x_lo);
    qkv_mfma_kernel<<<dim3(NTOK / 128, F3 / 128), 256, 0, stream>>>(
        x_hi, x_lo, wq, q_hi, q_lo, k_hi, k_lo, v_th, v_tl);
    attn_kernel<<<dim3(8, BH), 256, 0, stream>>>(
        q_hi, q_lo, k_hi, k_lo, v_th, v_tl, o_hi, o_lo);
    proj_mfma_kernel<<<dim3(NTOK / 128, DMODEL / 128), 256, 0, stream>>>(
        o_hi, o_lo, wo, bo, out);
}

// Round 5
// 388.461 us; speedup vs baseline: 3.0002x; 1.1705x over previous
//
#include <hip/hip_runtime.h>
#include <math.h>

#define NH 8
#define HD 64
#define NSEQ 1024
#define DMODEL 512
#define F3 1536
#define NTOK 16384
#define BH 128    // (B*T)*NH = 16*8
#define KVP 72    // attn K/V LDS pitch (bf16)
#define TP 136    // qkv epilogue transpose pitch (bf16)
#define QSCALE 0.1803368867f  // 0.125 * log2(e), folded into q; p = exp2(s')

typedef __attribute__((ext_vector_type(8))) short bf16x8;
typedef __attribute__((ext_vector_type(4))) float f32x4;
#define MFMA16(a, b, c) __builtin_amdgcn_mfma_f32_16x16x32_bf16(a, b, c, 0, 0, 0)

__device__ __forceinline__ float freq_of(int j) {
    return 3.14159265358979323846f * (1.0f + (float)j * (127.0f / 15.0f));
}
__device__ __forceinline__ unsigned short bf16_hi(float x) {
    unsigned u = __builtin_bit_cast(unsigned, x);
    return (unsigned short)(u >> 16);   // truncation split; residual goes to lo
}
__device__ __forceinline__ unsigned short bf16_rtn(float x) {
    unsigned u = __builtin_bit_cast(unsigned, x);
    return (unsigned short)((u + 0x7FFF + ((u >> 16) & 1)) >> 16);
}
__device__ __forceinline__ float bf16_tofloat(unsigned short h) {
    unsigned u = ((unsigned)h) << 16;
    return __builtin_bit_cast(float, u);
}
__device__ __forceinline__ void gld_lds16(unsigned short* lds_dst, const unsigned short* gsrc) {
    __builtin_amdgcn_global_load_lds(
        (const __attribute__((address_space(1))) unsigned int*)gsrc,
        (__attribute__((address_space(3))) unsigned int*)lds_dst,
        16, 0, 0);
}

// ---------------- Kernel 0: split fp32 -> bf16 hi/lo ----------------
__global__ __launch_bounds__(256) void split_kernel(
        const float* __restrict__ src, unsigned short* __restrict__ hi,
        unsigned short* __restrict__ lo) {
    const int i = blockIdx.x * 256 + threadIdx.x;
    const float4 v = ((const float4*)src)[i];
    ushort4 h, l;
    h.x = bf16_hi(v.x); l.x = bf16_hi(v.x - bf16_tofloat(h.x));
    h.y = bf16_hi(v.y); l.y = bf16_hi(v.y - bf16_tofloat(h.y));
    h.z = bf16_hi(v.z); l.z = bf16_hi(v.z - bf16_tofloat(h.z));
    h.w = bf16_hi(v.w); l.w = bf16_hi(v.w - bf16_tofloat(h.w));
    ((ushort4*)hi)[i] = h;
    ((ushort4*)lo)[i] = l;
}

// ---- shared 2-stage pipelined GEMM core: 128x128 tile, BK=32, K=512 ----
// A [row][512] hi/lo, B [row][512] hi/lo, all pre-split bf16.
// Stage = {Ah,Al,Bh,Bl} 4x8KB = 32 KB; 2 stages ping-pong. One barrier/iter:
// loads for kt+1 are issued before compute(kt), so the vmcnt(0) drain at the
// next barrier waits on loads that have been in flight for a full compute phase.
__device__ __forceinline__ void gemm_pipe_128(
        const unsigned short* __restrict__ a_hi, const unsigned short* __restrict__ a_lo,
        const unsigned short* __restrict__ b_hi, const unsigned short* __restrict__ b_lo,
        char* lds, int m0, int f0, int t, f32x4 acc[4][4]) {
    const int w = t >> 6, lane = t & 63, l15 = lane & 15, quad = lane >> 4;
    const int mw = (w & 1) * 64, nw = (w >> 1) * 64;

    auto issue = [&](int kt, int stage) {
        unsigned short* S = (unsigned short*)(lds + stage * 32768);
        const int k0 = kt * 32;
        #pragma unroll
        for (int ii = 0; ii < 8; ii++) {
            const int idx = w * 8 + ii;       // 0..31, wave-uniform
            const int part = idx >> 3;        // 0:Ah 1:Al 2:Bh 3:Bl
            const int chunk = idx & 7;
            const unsigned short* src = (part == 0) ? a_hi : (part == 1) ? a_lo
                                      : (part == 2) ? b_hi : b_lo;
            const int row0 = (part < 2) ? m0 : f0;
            const unsigned short* g = src +
                (size_t)(row0 + chunk * 16 + (lane >> 2)) * DMODEL + k0 + (lane & 3) * 8;
            gld_lds16(S + part * 4096 + chunk * 512, g);
        }
    };

    issue(0, 0);
    for (int kt = 0; kt < 16; kt++) {
        __syncthreads();                      // drains stage-kt loads (in flight since kt-1)
        if (kt < 15) issue(kt + 1, (kt + 1) & 1);
        unsigned short* S = (unsigned short*)(lds + (kt & 1) * 32768);
        const unsigned short* Ah = S;
        const unsigned short* Al = S + 4096;
        const unsigned short* Bh = S + 8192;
        const unsigned short* Bl = S + 12288;
        bf16x8 afh[4], afl[4], bfh[4], bfl[4];
        #pragma unroll
        for (int mt = 0; mt < 4; mt++) {
            const int off = (mw + mt * 16 + l15) * 32 + quad * 8;
            afh[mt] = *(const bf16x8*)&Ah[off];
            afl[mt] = *(const bf16x8*)&Al[off];
        }
        #pragma unroll
        for (int nt = 0; nt < 4; nt++) {
            const int off = (nw + nt * 16 + l15) * 32 + quad * 8;
            bfh[nt] = *(const bf16x8*)&Bh[off];
            bfl[nt] = *(const bf16x8*)&Bl[off];
        }
        #pragma unroll
        for (int mt = 0; mt < 4; mt++)
            #pragma unroll
            for (int nt = 0; nt < 4; nt++) {
                acc[mt][nt] = MFMA16(afh[mt], bfh[nt], acc[mt][nt]);
                acc[mt][nt] = MFMA16(afh[mt], bfl[nt], acc[mt][nt]);
                acc[mt][nt] = MFMA16(afl[mt], bfh[nt], acc[mt][nt]);
            }
    }
    __syncthreads();                          // LDS free for epilogue reuse
}

// ---------------- Kernel 1: QKV GEMM (pipelined) + RoPE ----------------
__global__ __launch_bounds__(256) void qkv_mfma_kernel(
        const unsigned short* __restrict__ x_hi, const unsigned short* __restrict__ x_lo,
        const unsigned short* __restrict__ wq_hi, const unsigned short* __restrict__ wq_lo,
        unsigned short* __restrict__ q_hi, unsigned short* __restrict__ q_lo,
        unsigned short* __restrict__ k_hi, unsigned short* __restrict__ k_lo,
        unsigned short* __restrict__ v_th) {
    __shared__ __align__(16) char lds[65536 + 4608];
    unsigned short* T = (unsigned short*)lds;             // 128 x TP transpose buffer
    float* t_cy = (float*)(lds + 65536);                  // [4][16]
    float* t_sy = t_cy + 64;
    float* t_cx = t_sy + 64;                              // [32][16]
    float* t_sx = t_cx + 512;

    const int m0 = blockIdx.x * 128;
    const int f0 = blockIdx.y * 128;
    const int t = threadIdx.x;
    const int w = t >> 6, lane = t & 63, l15 = lane & 15, quad = lane >> 4;
    const int mw = (w & 1) * 64, nw = (w >> 1) * 64;
    const int sel = f0 >> 9;                // 0=q,1=k,2=v
    const int bt = m0 >> 10;
    const int n0 = m0 & 1023;

    if (sel != 2) {
        for (int idx = t; idx < 576; idx += 256) {
            if (idx < 64) {
                const int yi = idx >> 4, j = idx & 15;
                const float pos = -1.0f + (float)((n0 >> 5) + yi) * (2.0f / 31.0f);
                float sv, cv; sincosf(pos * freq_of(j), &sv, &cv);
                t_sy[idx] = sv; t_cy[idx] = cv;
            } else {
                const int k2 = idx - 64, xi = k2 >> 4, j = k2 & 15;
                const float pos = -1.0f + (float)xi * (2.0f / 31.0f);
                float sv, cv; sincosf(pos * freq_of(j), &sv, &cv);
                t_sx[k2] = sv; t_cx[k2] = cv;
            }
        }
    }

    f32x4 acc[4][4];
    #pragma unroll
    for (int mt = 0; mt < 4; mt++)
        #pragma unroll
        for (int nt = 0; nt < 4; nt++) acc[mt][nt] = (f32x4){0.f, 0.f, 0.f, 0.f};

    gemm_pipe_128(x_hi, x_lo, wq_hi, wq_lo, lds, m0, f0, t, acc);

    // rope in place (q,k); q additionally scaled by QSCALE so attn uses exp2
    if (sel != 2) {
        const float post = (sel == 0) ? QSCALE : 1.0f;
        #pragma unroll
        for (int mt = 0; mt < 4; mt++)
            #pragma unroll
            for (int nt = 0; nt < 4; nt++)
                #pragma unroll
                for (int rr = 0; rr < 4; rr++) {
                    const int ml = mw + mt * 16 + quad * 4 + rr;
                    const int dd = (nw + nt * 16 + l15) & 63;
                    const int j0 = (dd & 31) >> 1;
                    float c, s;
                    if (dd < 32) { c = t_cy[(ml >> 5) * 16 + j0]; s = t_sy[(ml >> 5) * 16 + j0]; }
                    else         { c = t_cx[(ml & 31) * 16 + j0]; s = t_sx[(ml & 31) * 16 + j0]; }
                    const float v = acc[mt][nt][rr];
                    const float pv = __shfl_xor(v, 1);
                    acc[mt][nt][rr] = ((l15 & 1) ? (v * c + pv * s) : (v * c - pv * s)) * post;
                }
    }

    const int npass = (sel == 2) ? 1 : 2;
    for (int pass = 0; pass < npass; pass++) {
        #pragma unroll
        for (int mt = 0; mt < 4; mt++)
            #pragma unroll
            for (int nt = 0; nt < 4; nt++)
                #pragma unroll
                for (int rr = 0; rr < 4; rr++) {
                    const int ml = mw + mt * 16 + quad * 4 + rr;
                    const int fl = nw + nt * 16 + l15;
                    const float v = acc[mt][nt][rr];
                    const unsigned short h = bf16_hi(v);
                    const unsigned short val = (pass == 0) ? h : bf16_hi(v - bf16_tofloat(h));
                    if (sel == 2) T[fl * TP + ml] = val;   // v: [f][n] rows
                    else          T[ml * TP + fl] = val;   // q/k: [n][f] rows
                }
        __syncthreads();
        if (sel == 2) {
            #pragma unroll
            for (int p = 0; p < 8; p++) {
                const int idx = p * 256 + t;
                const int fl = idx >> 4, g = (idx & 15) * 8;
                const int head = ((f0 + fl) >> 6) & 7;
                unsigned short* gp = v_th +
                    ((size_t)(bt * NH + head) * HD + (fl & 63)) * NSEQ + n0 + g;
                *(uint4*)gp = *(const uint4*)&T[fl * TP + g];
            }
        } else {
            unsigned short* dst = (sel == 0) ? ((pass == 0) ? q_hi : q_lo)
                                             : ((pass == 0) ? k_hi : k_lo);
            #pragma unroll
            for (int p = 0; p < 8; p++) {
                const int idx = p * 256 + t;
                const int ml = idx >> 4, g = (idx & 15) * 8;
                const int head = ((f0 + g) >> 6) & 7;
                unsigned short* gp = dst +
                    ((size_t)(bt * NH + head) * NSEQ + n0 + ml) * HD + (g & 63);
                *(uint4*)gp = *(const uint4*)&T[ml * TP + g];
            }
        }
        __syncthreads();
    }
}

// ---------------- Kernel 2: flash attention, no-max exp2 softmax ----------------
// V hi-only (v_lo dropped: its 2^-9 contribution matches P's own RTN error scale).
__global__ __launch_bounds__(256, 3) void attn_kernel(
        const unsigned short* __restrict__ q_hi, const unsigned short* __restrict__ q_lo,
        const unsigned short* __restrict__ k_hi, const unsigned short* __restrict__ k_lo,
        const unsigned short* __restrict__ v_th,
        unsigned short* __restrict__ o_hi, unsigned short* __restrict__ o_lo) {
    __shared__ unsigned short Ks[128 * KVP];  // rows 0..63: K_hi, 64..127: K_lo
    __shared__ unsigned short Vsh[64 * KVP];  // V^T hi
    __shared__ unsigned short Ps[128 * 64];   // P, xor-swizzled cols, wave-private rows

    const int qt = blockIdx.x;     // 0..7
    const int bh = blockIdx.y;     // 0..127
    const int t = threadIdx.x;
    const int w = t >> 6;
    const int lane = t & 63;
    const int l15 = lane & 15;
    const int quad = lane >> 4;

    const size_t bh_nd = (size_t)bh * NSEQ * HD;
    const size_t bh_dn = (size_t)bh * HD * NSEQ;

    bf16x8 qfh[2][2], qfl[2][2];
    #pragma unroll
    for (int mf = 0; mf < 2; mf++) {
        const size_t rbase = bh_nd + (size_t)(qt * 128 + w * 32 + mf * 16 + l15) * HD;
        #pragma unroll
        for (int ks = 0; ks < 2; ks++) {
            qfh[mf][ks] = *(const bf16x8*)(q_hi + rbase + ks * 32 + quad * 8);
            qfl[mf][ks] = *(const bf16x8*)(q_lo + rbase + ks * 32 + quad * 8);
        }
    }

    const bf16x8 ones = {(short)0x3F80, (short)0x3F80, (short)0x3F80, (short)0x3F80,
                         (short)0x3F80, (short)0x3F80, (short)0x3F80, (short)0x3F80};

    f32x4 o_acc[2][4], l_acc[2];
    #pragma unroll
    for (int mf = 0; mf < 2; mf++) {
        l_acc[mf] = (f32x4){0.f, 0.f, 0.f, 0.f};
        #pragma unroll
        for (int dt = 0; dt < 4; dt++) o_acc[mf][dt] = (f32x4){0.f, 0.f, 0.f, 0.f};
    }

    for (int kt = 0; kt < 16; kt++) {
        __syncthreads();
        #pragma unroll
        for (int p = 0; p < 2; p++) {
            const int cc = t + p * 256;
            const int r = cc >> 3, off8 = (cc & 7) * 8;
            const size_t gk = bh_nd + (size_t)(kt * 64 + r) * HD + off8;
            *(uint4*)&Ks[r * KVP + off8]        = *(const uint4*)(k_hi + gk);
            *(uint4*)&Ks[(64 + r) * KVP + off8] = *(const uint4*)(k_lo + gk);
            const size_t gv = bh_dn + (size_t)r * NSEQ + kt * 64 + off8;
            *(uint4*)&Vsh[r * KVP + off8]       = *(const uint4*)(v_th + gv);
        }
        __syncthreads();

        // ---- S = Q K^T (hh+hl+lh), p = exp2(s), store P (bf16 RTN, swizzled) ----
        #pragma unroll
        for (int nt = 0; nt < 4; nt++) {
            bf16x8 kh[2], kl[2];
            #pragma unroll
            for (int ks = 0; ks < 2; ks++) {
                const int off = (nt * 16 + l15) * KVP + ks * 32 + quad * 8;
                kh[ks] = *(const bf16x8*)&Ks[off];
                kl[ks] = *(const bf16x8*)&Ks[64 * KVP + off];
            }
            #pragma unroll
            for (int mf = 0; mf < 2; mf++) {
                f32x4 s = (f32x4){0.f, 0.f, 0.f, 0.f};
                #pragma unroll
                for (int ks = 0; ks < 2; ks++) {
                    s = MFMA16(qfh[mf][ks], kh[ks], s);
                    s = MFMA16(qfh[mf][ks], kl[ks], s);
                    s = MFMA16(qfl[mf][ks], kh[ks], s);
                }
                const int prow_b = w * 32 + mf * 16 + quad * 4;
                const int col = nt * 16 + l15;
                #pragma unroll
                for (int r = 0; r < 4; r++) {
                    const int prow = prow_b + r;
                    const float pv = exp2f(s[r]);
                    Ps[prow * 64 + ((((col >> 3) ^ (prow & 7)) << 3) | (col & 7))] =
                        bf16_rtn(pv);
                }
            }
        }

        // ---- O += P V, l += P 1 (P wave-private: no barrier needed) ----
        bf16x8 pf[2][2];
        #pragma unroll
        for (int mf = 0; mf < 2; mf++) {
            const int prow = w * 32 + mf * 16 + l15;
            #pragma unroll
            for (int ks = 0; ks < 2; ks++)
                pf[mf][ks] = *(const bf16x8*)&Ps[prow * 64 +
                                (((ks * 4 + quad) ^ (prow & 7)) << 3)];
            l_acc[mf] = MFMA16(pf[mf][0], ones, l_acc[mf]);
            l_acc[mf] = MFMA16(pf[mf][1], ones, l_acc[mf]);
        }
        #pragma unroll
        for (int dt = 0; dt < 4; dt++) {
            bf16x8 vh[2];
            #pragma unroll
            for (int ks = 0; ks < 2; ks++)
                vh[ks] = *(const bf16x8*)&Vsh[(dt * 16 + l15) * KVP + ks * 32 + quad * 8];
            #pragma unroll
            for (int mf = 0; mf < 2; mf++) {
                o_acc[mf][dt] = MFMA16(pf[mf][0], vh[0], o_acc[mf][dt]);
                o_acc[mf][dt] = MFMA16(pf[mf][1], vh[1], o_acc[mf][dt]);
            }
        }
    }

    // ---- epilogue: normalize by l, split bf16 hi/lo for proj ----
    const int btq = bh >> 3, head = bh & 7;
    #pragma unroll
    for (int mf = 0; mf < 2; mf++)
        #pragma unroll
        for (int r = 0; r < 4; r++) {
            const float inv = 1.0f / l_acc[mf][r];
            const int row = qt * 128 + w * 32 + mf * 16 + quad * 4 + r;
            #pragma unroll
            for (int dt = 0; dt < 4; dt++) {
                const float val = o_acc[mf][dt][r] * inv;
                const unsigned short h = bf16_hi(val);
                const size_t off =
                    ((size_t)(btq * NSEQ + row)) * DMODEL + head * HD + dt * 16 + l15;
                o_hi[off] = h;
                o_lo[off] = bf16_hi(val - bf16_tofloat(h));
            }
        }
}

// ---------------- Kernel 3: output projection (pipelined) ----------------
__global__ __launch_bounds__(256) void proj_mfma_kernel(
        const unsigned short* __restrict__ o_hi, const unsigned short* __restrict__ o_lo,
        const unsigned short* __restrict__ wo_hi, const unsigned short* __restrict__ wo_lo,
        const float* __restrict__ b_out, float* __restrict__ out) {
    __shared__ __align__(16) char lds[65536];

    const int m0 = blockIdx.x * 128;
    const int f0 = blockIdx.y * 128;
    const int t = threadIdx.x;
    const int w = t >> 6, lane = t & 63, l15 = lane & 15, quad = lane >> 4;
    const int mw = (w & 1) * 64, nw = (w >> 1) * 64;

    f32x4 acc[4][4];
    #pragma unroll
    for (int mt = 0; mt < 4; mt++)
        #pragma unroll
        for (int nt = 0; nt < 4; nt++) acc[mt][nt] = (f32x4){0.f, 0.f, 0.f, 0.f};

    gemm_pipe_128(o_hi, o_lo, wo_hi, wo_lo, lds, m0, f0, t, acc);

    float bias_v[4];
    #pragma unroll
    for (int nt = 0; nt < 4; nt++) bias_v[nt] = b_out[f0 + nw + nt * 16 + l15];
    #pragma unroll
    for (int mt = 0; mt < 4; mt++)
        #pragma unroll
        for (int nt = 0; nt < 4; nt++)
            #pragma unroll
            for (int rr = 0; rr < 4; rr++) {
                const int m = m0 + mw + mt * 16 + quad * 4 + rr;
                out[(size_t)m * DMODEL + f0 + nw + nt * 16 + l15] =
                    acc[mt][nt][rr] + bias_v[nt];
            }
}

extern "C" void kernel_launch(void* const* d_in, const int* in_sizes, int n_in,
                              void* d_out, int out_size, void* d_ws, size_t ws_size,
                              hipStream_t stream) {
    const float* x  = (const float*)d_in[0];
    const float* wq = (const float*)d_in[1];
    const float* wo = (const float*)d_in[2];
    const float* bo = (const float*)d_in[3];
    float* out = (float*)d_out;

    const size_t per = (size_t)BH * NSEQ * HD;   // 8,388,608 elements
    unsigned short* x_hi = (unsigned short*)d_ws;   // reused as o_hi after qkv
    unsigned short* x_lo = x_hi + per;              // reused as o_lo
    unsigned short* q_hi = x_lo + per;
    unsigned short* q_lo = q_hi + per;
    unsigned short* k_hi = q_lo + per;
    unsigned short* k_lo = k_hi + per;
    unsigned short* v_th = k_lo + per;
    unsigned short* wq_hi = v_th + per;             // 786,432 els
    unsigned short* wq_lo = wq_hi + (size_t)F3 * DMODEL;
    unsigned short* wo_hi = wq_lo + (size_t)F3 * DMODEL;
    unsigned short* wo_lo = wo_hi + (size_t)DMODEL * DMODEL;  // ends < 8*per: 116 MiB total
    unsigned short* o_hi = x_hi;
    unsigned short* o_lo = x_lo;

    split_kernel<<<dim3((int)(per / 1024)), 256, 0, stream>>>(x, x_hi, x_lo);
    split_kernel<<<dim3(F3 * DMODEL / 1024), 256, 0, stream>>>(wq, wq_hi, wq_lo);
    split_kernel<<<dim3(DMODEL * DMODEL / 1024), 256, 0, stream>>>(wo, wo_hi, wo_lo);
    qkv_mfma_kernel<<<dim3(NTOK / 128, F3 / 128), 256, 0, stream>>>(
        x_hi, x_lo, wq_hi, wq_lo, q_hi, q_lo, k_hi, k_lo, v_th);
    attn_kernel<<<dim3(8, BH), 256, 0, stream>>>(
        q_hi, q_lo, k_hi, k_lo, v_th, o_hi, o_lo);
    proj_mfma_kernel<<<dim3(NTOK / 128, DMODEL / 128), 256, 0, stream>>>(
        o_hi, o_lo, wo_hi, wo_lo, bo, out);
}